// Round 5
// baseline (338.247 us; speedup 1.0000x reference)
//
#include <hip/hip_runtime.h>
#include <hip/hip_bf16.h>

// AttentionBlock: GroupNorm -> QKV -> MHA (8 heads, hd=64, s=1024) -> out proj -> +xn
// Inputs/outputs FP32; internally bf16 for MFMA.
//
//   1. transpose+cast w_qkv -> wqkvT bf16 [1536][512]; w_out -> woutT [512][512]
//   2. groupnorm: xn bf16
//   3. GEMM qkv: writes kq[row][h*128 + (q:0..63 | k:64..127)] (q pre-scaled 1/8)
//      and vT[b][h][d][s]  (MFMA 16x16x32, A staged via global_load_lds w=16)
//   4. attention: S^T = K@Q^T trick -> exp'd regs ARE the PV A-fragment of
//      mfma_16x16x16 (zero LDS, zero in-loop shuffles); no-max softmax;
//      l via per-lane adds + epilogue shfl; 16 q-rows/wave (4 waves/SIMD)
//   5. GEMM out = attn @ w_out + b + xn -> fp32 d_out
//
// ws: xn 8MB @0 | kq 16MB @8 | attn 8MB @24 | vT 8MB @32 | wqkvT 1.5MB @40 | woutT .5MB @41.5

#define B_    8
#define S_    1024
#define C_    512
#define NH    8
#define HD    64
#define QKVC  1536
#define GROUPS 32
#define GSIZE  16
#define EPSV   1e-5f

using frag8 = __attribute__((ext_vector_type(8))) short;   // 8 bf16 = 4 VGPR
using frag4 = __attribute__((ext_vector_type(4))) short;   // 4 bf16 = 2 VGPR
using f32x4 = __attribute__((ext_vector_type(4))) float;

__device__ __forceinline__ float bf2f(unsigned short u) {
    union { unsigned int i; float f; } v; v.i = ((unsigned int)u) << 16; return v.f;
}
__device__ __forceinline__ unsigned short f2bf(float f) {
    union { float f; unsigned int i; } v; v.f = f;
    unsigned int x = v.i;
    return (unsigned short)((x + 0x7fffu + ((x >> 16) & 1u)) >> 16);
}
__device__ __forceinline__ f32x4 zero4() {
    f32x4 z; z[0] = 0.f; z[1] = 0.f; z[2] = 0.f; z[3] = 0.f; return z;
}

// ---------------------------------------------------------------- transpose
__global__ __launch_bounds__(256) void transpose_kernel(
        const float* __restrict__ in, unsigned short* __restrict__ out,
        int K, int N) {
    __shared__ float tile[32][33];
    int n0 = blockIdx.x * 32, k0 = blockIdx.y * 32;
    int t = threadIdx.x;
    for (int i = 0; i < 4; ++i) {
        int idx = t + i * 256; int r = idx >> 5, c = idx & 31;
        tile[r][c] = in[(size_t)(k0 + r) * N + n0 + c];
    }
    __syncthreads();
    for (int i = 0; i < 4; ++i) {
        int idx = t + i * 256; int r = idx >> 5, c = idx & 31;
        out[(size_t)(n0 + r) * K + k0 + c] = f2bf(tile[c][r]);
    }
}

// ---------------------------------------------------------------- groupnorm
__global__ __launch_bounds__(256) void gn_kernel(
        const float* __restrict__ x,
        const float* __restrict__ scale,
        const float* __restrict__ bias,
        unsigned short* __restrict__ xn) {
    int bg = blockIdx.x;
    int b = bg >> 5, g = bg & 31;
    const float* xb = x + (size_t)b * S_ * C_;
    int t = threadIdx.x;

    float sum = 0.f, ss = 0.f;
    for (int i = 0; i < 16; ++i) {
        int idx = t + i * 256;
        int row = idx >> 2, j = idx & 3;
        float4 v = *(const float4*)(xb + (size_t)row * C_ + g * GSIZE + j * 4);
        sum += v.x + v.y + v.z + v.w;
        ss  += v.x * v.x + v.y * v.y + v.z * v.z + v.w * v.w;
    }
    for (int off = 1; off < 64; off <<= 1) {
        sum += __shfl_xor(sum, off);
        ss  += __shfl_xor(ss,  off);
    }
    __shared__ float s_sum[4], s_ss[4];
    int wid = t >> 6;
    if ((t & 63) == 0) { s_sum[wid] = sum; s_ss[wid] = ss; }
    __syncthreads();
    sum = s_sum[0] + s_sum[1] + s_sum[2] + s_sum[3];
    ss  = s_ss[0]  + s_ss[1]  + s_ss[2]  + s_ss[3];
    float mean = sum * (1.f / 16384.f);
    float var  = ss * (1.f / 16384.f) - mean * mean;
    float rinv = rsqrtf(var + EPSV);

    float sc[16], bi[16];
    for (int u = 0; u < 16; ++u) {
        sc[u] = scale[g * GSIZE + u];
        bi[u] = bias[g * GSIZE + u];
    }
    for (int i = 0; i < 16; ++i) {
        int idx = t + i * 256;
        int row = idx >> 2, j = idx & 3;
        float4 v = *(const float4*)(xb + (size_t)row * C_ + g * GSIZE + j * 4);
        int c0 = j * 4;
        float f0 = (v.x - mean) * rinv * sc[c0 + 0] + bi[c0 + 0];
        float f1 = (v.y - mean) * rinv * sc[c0 + 1] + bi[c0 + 1];
        float f2 = (v.z - mean) * rinv * sc[c0 + 2] + bi[c0 + 2];
        float f3 = (v.w - mean) * rinv * sc[c0 + 3] + bi[c0 + 3];
        uint2 o;
        o.x = (unsigned int)f2bf(f0) | ((unsigned int)f2bf(f1) << 16);
        o.y = (unsigned int)f2bf(f2) | ((unsigned int)f2bf(f3) << 16);
        *(uint2*)(xn + (size_t)b * S_ * C_ + (size_t)row * C_ + g * GSIZE + c0) = o;
    }
}

// ---------------------------------------------------------------- GEMM
// 128x128 tile, 4 waves x 64x64, BK=32, A staged via global_load_lds w=16.
// MODE 0: qkv epilogue -> kq (q scaled 1/8, k plain) + vT[b][h][d][s]
// MODE 1: fp32 out + bf16 resid
template<int MODE>
__global__ __launch_bounds__(256) void gemm_kernel(
        const unsigned short* __restrict__ A,
        const unsigned short* __restrict__ Bt,
        const float* __restrict__ bias,
        const unsigned short* __restrict__ resid,
        unsigned short* __restrict__ outA,   // MODE0: kq [M][1024]
        unsigned short* __restrict__ outV,   // MODE0: vT [b][h][64][1024]
        float* __restrict__ outF,            // MODE1: fp32 [M][N]
        int M, int N, int K) {
    __shared__ unsigned short As[128 * 32];
    int m0 = blockIdx.y * 128, n0 = blockIdx.x * 128;
    int t = threadIdx.x;
    int wid = t >> 6, lane = t & 63;
    int quad = lane >> 4, l16 = lane & 15;
    int wm = (wid >> 1) * 64, wn = (wid & 1) * 64;

    f32x4 acc[4][4];
    for (int mi = 0; mi < 4; ++mi)
        for (int ni = 0; ni < 4; ++ni) acc[mi][ni] = zero4();

    for (int k0 = 0; k0 < K; k0 += 32) {
        __syncthreads();
        for (int i = 0; i < 2; ++i) {
            int idx = i * 256 + t;                 // 0..511 16B slots
            int row = idx >> 2, seg = idx & 3;
            const unsigned short* gp = A + (size_t)(m0 + row) * K + k0 + seg * 8;
            unsigned short* lp = As + (size_t)(i * 256 + wid * 64) * 8;  // wave-uniform
            __builtin_amdgcn_global_load_lds(
                (const __attribute__((address_space(1))) void*)gp,
                (__attribute__((address_space(3))) void*)lp, 16, 0, 0);
        }
        __syncthreads();

        frag8 bfrag[4], afrag[4];
        for (int ni = 0; ni < 4; ++ni)
            bfrag[ni] = *(const frag8*)(Bt + (size_t)(n0 + wn + ni * 16 + l16) * K + k0 + quad * 8);
        for (int mi = 0; mi < 4; ++mi)
            afrag[mi] = *(const frag8*)(&As[(wm + mi * 16 + l16) * 32 + quad * 8]);

        for (int mi = 0; mi < 4; ++mi)
            for (int ni = 0; ni < 4; ++ni)
                acc[mi][ni] = __builtin_amdgcn_mfma_f32_16x16x32_bf16(
                    afrag[mi], bfrag[ni], acc[mi][ni], 0, 0, 0);
    }

    for (int ni = 0; ni < 4; ++ni) {
        int c0 = n0 + wn + ni * 16;                 // tile base col (multiple of 16)
        float bv = bias[c0 + l16];
        if (MODE == 0) {
            int h = c0 / 192, rr = c0 % 192;        // section uniform per tile
            if (rr >= 128) {
                // V -> vT[b][h][d][s], packed ushort4 along s (r contiguous)
                int d = rr - 128 + l16;
                int bidx = m0 >> 10;
                unsigned short* vp = outV + (((size_t)bidx * NH + h) * HD + d) * S_
                                   + (m0 & 1023) + wm + quad * 4;
                for (int mi = 0; mi < 4; ++mi) {
                    ushort4 pk;
                    pk.x = f2bf(acc[mi][ni][0] + bv);
                    pk.y = f2bf(acc[mi][ni][1] + bv);
                    pk.z = f2bf(acc[mi][ni][2] + bv);
                    pk.w = f2bf(acc[mi][ni][3] + bv);
                    *(ushort4*)(vp + mi * 16) = pk;
                }
            } else {
                float scl = (rr < 64) ? 0.125f : 1.0f;
                int colk = h * 128 + rr + l16;
                for (int mi = 0; mi < 4; ++mi)
                    for (int r = 0; r < 4; ++r) {
                        int row = m0 + wm + mi * 16 + quad * 4 + r;
                        outA[(size_t)row * 1024 + colk] = f2bf((acc[mi][ni][r] + bv) * scl);
                    }
            }
        } else {
            int col = c0 + l16;
            for (int mi = 0; mi < 4; ++mi)
                for (int r = 0; r < 4; ++r) {
                    int row = m0 + wm + mi * 16 + quad * 4 + r;
                    float v = acc[mi][ni][r] + bv + bf2f(resid[(size_t)row * N + col]);
                    outF[(size_t)row * N + col] = v;
                }
        }
    }
}

// ---------------------------------------------------------------- attention
// grid 1024 (XCD-swizzled: 16 q-tiles of each (b,h) share an XCD), 4 waves,
// 16 q-rows/wave, 32 keys/iter. S^T = K@Q^T so exp'd score regs are directly
// the A-fragment of mfma_16x16x16 PV. No LDS, no in-loop cross-lane ops.
__global__ __launch_bounds__(256) void attn_kernel(
        const unsigned short* __restrict__ kq,   // [b*s][h*128 + (q|k)]
        const unsigned short* __restrict__ vT,   // [b][h][d][s]
        unsigned short* __restrict__ attn_out) { // [b][s][512]
    int i = blockIdx.x;
    int xcd = i & 7, slot = i >> 3;              // slot 0..127
    int bh = xcd * 8 + (slot >> 4);              // 8 (b,h) pairs per XCD
    int qt = slot & 15;
    int b = bh >> 3, h = bh & 7;

    int t = threadIdx.x;
    int wid = t >> 6, lane = t & 63, quad = lane >> 4, l16 = lane & 15;
    int q0 = qt * 64 + wid * 16;

    // Q B-fragment: B[n=q=l16][k=d=quad*8+j]
    const unsigned short* qrow = kq + ((size_t)b * S_ + q0 + l16) * 1024 + h * 128;
    frag8 qf0 = *(const frag8*)(qrow + quad * 8);
    frag8 qf1 = *(const frag8*)(qrow + 32 + quad * 8);

    const unsigned short* kbase = kq + (size_t)b * S_ * 1024 + h * 128 + 64;
    const unsigned short* vbase = vT + ((size_t)b * NH + h) * HD * S_;

    f32x4 o[4];
    for (int dt = 0; dt < 4; ++dt) o[dt] = zero4();
    float l_acc = 0.f;

    // K A-fragment prefetch ping-pong: A[m=key=l16][k=d=quad*8+j]
    frag8 kf[2][4];
    {
        const unsigned short* kr = kbase + (size_t)l16 * 1024 + quad * 8;
        kf[0][0] = *(const frag8*)(kr);
        kf[0][1] = *(const frag8*)(kr + 32);
        kf[0][2] = *(const frag8*)(kr + 16 * 1024);
        kf[0][3] = *(const frag8*)(kr + 16 * 1024 + 32);
    }

    #pragma unroll 2
    for (int it = 0; it < S_ / 32; ++it) {
        int j0 = it * 32;
        int cur = it & 1, nxt = cur ^ 1;

        if (it < S_ / 32 - 1) {
            const unsigned short* kr = kbase + (size_t)(j0 + 32 + l16) * 1024 + quad * 8;
            kf[nxt][0] = *(const frag8*)(kr);
            kf[nxt][1] = *(const frag8*)(kr + 32);
            kf[nxt][2] = *(const frag8*)(kr + 16 * 1024);
            kf[nxt][3] = *(const frag8*)(kr + 16 * 1024 + 32);
        }

        // V^T B-fragments for PV (issued early, consumed after exp):
        // B[n=d=l16 within dt-tile][k=key=quad*4+j]
        frag4 vf[4][2];
        for (int dt = 0; dt < 4; ++dt) {
            const unsigned short* vp = vbase + (size_t)(dt * 16 + l16) * S_ + j0 + quad * 4;
            vf[dt][0] = *(const frag4*)(vp);
            vf[dt][1] = *(const frag4*)(vp + 16);
        }

        // S^T tiles: D[m=key][n=q], key tile t16 in {0,16}
        f32x4 st0 = zero4(), st1 = zero4();
        st0 = __builtin_amdgcn_mfma_f32_16x16x32_bf16(kf[cur][0], qf0, st0, 0, 0, 0);
        st0 = __builtin_amdgcn_mfma_f32_16x16x32_bf16(kf[cur][1], qf1, st0, 0, 0, 0);
        st1 = __builtin_amdgcn_mfma_f32_16x16x32_bf16(kf[cur][2], qf0, st1, 0, 0, 0);
        st1 = __builtin_amdgcn_mfma_f32_16x16x32_bf16(kf[cur][3], qf1, st1, 0, 0, 0);

        // exp in-register; lane (quad,l16) holds P[q=l16][key=t16+quad*4+r]
        float p0[4], p1[4];
        for (int r = 0; r < 4; ++r) {
            p0[r] = __expf(st0[r]);
            p1[r] = __expf(st1[r]);
            l_acc += p0[r] + p1[r];
        }
        frag4 pf0, pf1;
        for (int r = 0; r < 4; ++r) {
            pf0[r] = (short)f2bf(p0[r]);
            pf1[r] = (short)f2bf(p1[r]);
        }

        // PV: D[m=q][n=d] += P(A-frag) * V^T(B-frag), K=16 per tile
        for (int dt = 0; dt < 4; ++dt) {
            o[dt] = __builtin_amdgcn_mfma_f32_16x16x16bf16_1k(pf0, vf[dt][0], o[dt], 0, 0, 0);
            o[dt] = __builtin_amdgcn_mfma_f32_16x16x16bf16_1k(pf1, vf[dt][1], o[dt], 0, 0, 0);
        }
    }

    // l[q]: per-lane partials hold q=l16, keys subset; reduce across quads
    float l_red = l_acc;
    l_red += __shfl_xor(l_red, 16);
    l_red += __shfl_xor(l_red, 32);

    // O C-layout: lane(quad,l16) holds O[q=quad*4+r][d=dt*16+l16]
    float inv[4];
    for (int r = 0; r < 4; ++r)
        inv[r] = 1.0f / __shfl(l_red, quad * 4 + r);

    for (int dt = 0; dt < 4; ++dt)
        for (int r = 0; r < 4; ++r) {
            int qrw = q0 + quad * 4 + r;
            int ch = h * HD + dt * 16 + l16;
            attn_out[((size_t)b * S_ + qrw) * C_ + ch] = f2bf(o[dt][r] * inv[r]);
        }
}

// ---------------------------------------------------------------- launch
extern "C" void kernel_launch(void* const* d_in, const int* in_sizes, int n_in,
                              void* d_out, int out_size, void* d_ws, size_t ws_size,
                              hipStream_t stream) {
    const float* x        = (const float*)d_in[0];
    const float* gn_scale = (const float*)d_in[2];
    const float* gn_bias  = (const float*)d_in[3];
    const float* w_qkv    = (const float*)d_in[4];
    const float* b_qkv    = (const float*)d_in[5];
    const float* w_out    = (const float*)d_in[6];
    const float* b_out    = (const float*)d_in[7];
    float* out = (float*)d_out;

    char* ws = (char*)d_ws;
    unsigned short* xn    = (unsigned short*)(ws);                          // 8 MB
    unsigned short* kq    = (unsigned short*)(ws + ((size_t)8  << 20));     // 16 MB
    unsigned short* attn  = (unsigned short*)(ws + ((size_t)24 << 20));     // 8 MB
    unsigned short* vT    = (unsigned short*)(ws + ((size_t)32 << 20));     // 8 MB
    unsigned short* wqkvT = (unsigned short*)(ws + ((size_t)40 << 20));     // 1.5 MB
    unsigned short* woutT = (unsigned short*)(ws + ((size_t)40 << 20) + ((size_t)3 << 19)); // 0.5 MB

    transpose_kernel<<<dim3(QKVC / 32, C_ / 32), 256, 0, stream>>>(w_qkv, wqkvT, C_, QKVC);
    transpose_kernel<<<dim3(C_ / 32, C_ / 32), 256, 0, stream>>>(w_out, woutT, C_, C_);

    gn_kernel<<<dim3(B_ * GROUPS), 256, 0, stream>>>(x, gn_scale, gn_bias, xn);

    gemm_kernel<0><<<dim3(QKVC / 128, (B_ * S_) / 128), 256, 0, stream>>>(
        xn, wqkvT, b_qkv, nullptr, kq, vT, nullptr, B_ * S_, QKVC, C_);

    attn_kernel<<<dim3(1024), 256, 0, stream>>>(kq, vT, attn);

    gemm_kernel<1><<<dim3(C_ / 128, (B_ * S_) / 128), 256, 0, stream>>>(
        attn, woutT, b_out, xn, nullptr, nullptr, out, B_ * S_, C_, C_);
}

// Round 7
// 284.371 us; speedup vs baseline: 1.1895x; 1.1895x over previous
//
#include <hip/hip_runtime.h>
#include <hip/hip_bf16.h>

// AttentionBlock: GroupNorm -> QKV -> MHA (8 heads, hd=64, s=1024) -> out proj -> +xn
// Inputs/outputs FP32; internally bf16 for MFMA.
//
//   1. transpose+cast w_qkv -> wqkvT bf16 [1536][512]; w_out -> woutT [512][512]
//   2. groupnorm: xn bf16 (r4 version, byte-identical to the passing run)
//   3. GEMM qkv: writes kq[row][h*128 + (q:0..63 | k:64..127)] (q pre-scaled 1/8)
//      and vT[b][h][d][s]  (MFMA 16x16x32, A staged via global_load_lds w=16)
//   4. attention: 16 q-rows/wave (4 waves/SIMD), K ping-pong prefetch,
//      wave-private LDS P round-trip, ones-MFMA for l, no barriers
//   5. GEMM out = attn @ w_out + b + xn -> fp32 d_out
//
// ws: xn 8MB @0 | kq 16MB @8 | attn 8MB @24 | vT 8MB @32 | wqkvT 1.5MB @40 | woutT .5MB @41.5

#define B_    8
#define S_    1024
#define C_    512
#define NH    8
#define HD    64
#define QKVC  1536
#define GROUPS 32
#define GSIZE  16
#define EPSV   1e-5f

using frag8 = __attribute__((ext_vector_type(8))) short;   // 8 bf16 = 4 VGPR
using f32x4 = __attribute__((ext_vector_type(4))) float;

__device__ __forceinline__ float bf2f(unsigned short u) {
    union { unsigned int i; float f; } v; v.i = ((unsigned int)u) << 16; return v.f;
}
__device__ __forceinline__ unsigned short f2bf(float f) {
    union { float f; unsigned int i; } v; v.f = f;
    unsigned int x = v.i;
    return (unsigned short)((x + 0x7fffu + ((x >> 16) & 1u)) >> 16);
}
__device__ __forceinline__ f32x4 zero4() {
    f32x4 z; z[0] = 0.f; z[1] = 0.f; z[2] = 0.f; z[3] = 0.f; return z;
}

// ---------------------------------------------------------------- transpose
__global__ __launch_bounds__(256) void transpose_kernel(
        const float* __restrict__ in, unsigned short* __restrict__ out,
        int K, int N) {
    __shared__ float tile[32][33];
    int n0 = blockIdx.x * 32, k0 = blockIdx.y * 32;
    int t = threadIdx.x;
    for (int i = 0; i < 4; ++i) {
        int idx = t + i * 256; int r = idx >> 5, c = idx & 31;
        tile[r][c] = in[(size_t)(k0 + r) * N + n0 + c];
    }
    __syncthreads();
    for (int i = 0; i < 4; ++i) {
        int idx = t + i * 256; int r = idx >> 5, c = idx & 31;
        out[(size_t)(n0 + r) * K + k0 + c] = f2bf(tile[c][r]);
    }
}

// ---------------------------------------------------------------- groupnorm
// (r4 version — byte-identical to the passing run)
__global__ __launch_bounds__(256) void gn_kernel(
        const float* __restrict__ x,
        const float* __restrict__ scale,
        const float* __restrict__ bias,
        unsigned short* __restrict__ xn) {
    int bg = blockIdx.x;
    int b = bg >> 5, g = bg & 31;
    const float* xb = x + (size_t)b * S_ * C_;
    int t = threadIdx.x;

    float sum = 0.f, ss = 0.f;
    for (int i = 0; i < 16; ++i) {
        int idx = t + i * 256;
        int row = idx >> 2, j = idx & 3;
        float4 v = *(const float4*)(xb + (size_t)row * C_ + g * GSIZE + j * 4);
        sum += v.x + v.y + v.z + v.w;
        ss  += v.x * v.x + v.y * v.y + v.z * v.z + v.w * v.w;
    }
    for (int off = 1; off < 64; off <<= 1) {
        sum += __shfl_xor(sum, off);
        ss  += __shfl_xor(ss,  off);
    }
    __shared__ float s_sum[4], s_ss[4];
    int wid = t >> 6;
    if ((t & 63) == 0) { s_sum[wid] = sum; s_ss[wid] = ss; }
    __syncthreads();
    sum = s_sum[0] + s_sum[1] + s_sum[2] + s_sum[3];
    ss  = s_ss[0]  + s_ss[1]  + s_ss[2]  + s_ss[3];
    float mean = sum * (1.f / 16384.f);
    float var  = ss * (1.f / 16384.f) - mean * mean;
    float rinv = rsqrtf(var + EPSV);

    float sc[16], bi[16];
    for (int u = 0; u < 16; ++u) {
        sc[u] = scale[g * GSIZE + u];
        bi[u] = bias[g * GSIZE + u];
    }
    for (int i = 0; i < 16; ++i) {
        int idx = t + i * 256;
        int row = idx >> 2, j = idx & 3;
        float4 v = *(const float4*)(xb + (size_t)row * C_ + g * GSIZE + j * 4);
        int c0 = j * 4;
        float f0 = (v.x - mean) * rinv * sc[c0 + 0] + bi[c0 + 0];
        float f1 = (v.y - mean) * rinv * sc[c0 + 1] + bi[c0 + 1];
        float f2 = (v.z - mean) * rinv * sc[c0 + 2] + bi[c0 + 2];
        float f3 = (v.w - mean) * rinv * sc[c0 + 3] + bi[c0 + 3];
        uint2 o;
        o.x = (unsigned int)f2bf(f0) | ((unsigned int)f2bf(f1) << 16);
        o.y = (unsigned int)f2bf(f2) | ((unsigned int)f2bf(f3) << 16);
        *(uint2*)(xn + (size_t)b * S_ * C_ + (size_t)row * C_ + g * GSIZE + c0) = o;
    }
}

// ---------------------------------------------------------------- GEMM
// 128x128 tile, 4 waves x 64x64, BK=32, A staged via global_load_lds w=16.
// MODE 0: qkv epilogue -> kq (q scaled 1/8, k plain) + vT[b][h][d][s]
// MODE 1: fp32 out + bf16 resid
template<int MODE>
__global__ __launch_bounds__(256) void gemm_kernel(
        const unsigned short* __restrict__ A,
        const unsigned short* __restrict__ Bt,
        const float* __restrict__ bias,
        const unsigned short* __restrict__ resid,
        unsigned short* __restrict__ outA,   // MODE0: kq [M][1024]
        unsigned short* __restrict__ outV,   // MODE0: vT [b][h][64][1024]
        float* __restrict__ outF,            // MODE1: fp32 [M][N]
        int M, int N, int K) {
    __shared__ unsigned short As[128 * 32];
    int m0 = blockIdx.y * 128, n0 = blockIdx.x * 128;
    int t = threadIdx.x;
    int wid = t >> 6, lane = t & 63;
    int quad = lane >> 4, l16 = lane & 15;
    int wm = (wid >> 1) * 64, wn = (wid & 1) * 64;

    f32x4 acc[4][4];
    for (int mi = 0; mi < 4; ++mi)
        for (int ni = 0; ni < 4; ++ni) acc[mi][ni] = zero4();

    for (int k0 = 0; k0 < K; k0 += 32) {
        __syncthreads();
        for (int i = 0; i < 2; ++i) {
            int idx = i * 256 + t;                 // 0..511 16B slots
            int row = idx >> 2, seg = idx & 3;
            const unsigned short* gp = A + (size_t)(m0 + row) * K + k0 + seg * 8;
            unsigned short* lp = As + (size_t)(i * 256 + wid * 64) * 8;  // wave-uniform
            __builtin_amdgcn_global_load_lds(
                (const __attribute__((address_space(1))) void*)gp,
                (__attribute__((address_space(3))) void*)lp, 16, 0, 0);
        }
        __syncthreads();

        frag8 bfrag[4], afrag[4];
        for (int ni = 0; ni < 4; ++ni)
            bfrag[ni] = *(const frag8*)(Bt + (size_t)(n0 + wn + ni * 16 + l16) * K + k0 + quad * 8);
        for (int mi = 0; mi < 4; ++mi)
            afrag[mi] = *(const frag8*)(&As[(wm + mi * 16 + l16) * 32 + quad * 8]);

        for (int mi = 0; mi < 4; ++mi)
            for (int ni = 0; ni < 4; ++ni)
                acc[mi][ni] = __builtin_amdgcn_mfma_f32_16x16x32_bf16(
                    afrag[mi], bfrag[ni], acc[mi][ni], 0, 0, 0);
    }

    for (int ni = 0; ni < 4; ++ni) {
        int c0 = n0 + wn + ni * 16;                 // tile base col (multiple of 16)
        float bv = bias[c0 + l16];
        if (MODE == 0) {
            int h = c0 / 192, rr = c0 % 192;        // section uniform per tile
            if (rr >= 128) {
                // V -> vT[b][h][d][s], packed ushort4 along s (r contiguous)
                int d = rr - 128 + l16;
                int bidx = m0 >> 10;
                unsigned short* vp = outV + (((size_t)bidx * NH + h) * HD + d) * S_
                                   + (m0 & 1023) + wm + quad * 4;
                for (int mi = 0; mi < 4; ++mi) {
                    ushort4 pk;
                    pk.x = f2bf(acc[mi][ni][0] + bv);
                    pk.y = f2bf(acc[mi][ni][1] + bv);
                    pk.z = f2bf(acc[mi][ni][2] + bv);
                    pk.w = f2bf(acc[mi][ni][3] + bv);
                    *(ushort4*)(vp + mi * 16) = pk;
                }
            } else {
                float scl = (rr < 64) ? 0.125f : 1.0f;
                int colk = h * 128 + rr + l16;
                for (int mi = 0; mi < 4; ++mi)
                    for (int r = 0; r < 4; ++r) {
                        int row = m0 + wm + mi * 16 + quad * 4 + r;
                        outA[(size_t)row * 1024 + colk] = f2bf((acc[mi][ni][r] + bv) * scl);
                    }
            }
        } else {
            int col = c0 + l16;
            for (int mi = 0; mi < 4; ++mi)
                for (int r = 0; r < 4; ++r) {
                    int row = m0 + wm + mi * 16 + quad * 4 + r;
                    float v = acc[mi][ni][r] + bv + bf2f(resid[(size_t)row * N + col]);
                    outF[(size_t)row * N + col] = v;
                }
        }
    }
}

// ---------------------------------------------------------------- attention
// grid 1024, XCD-swizzled (16 q-tiles of each (b,h) share an XCD); 4 waves x
// 16 q-rows; 32 keys/iter; K ping-pong prefetch; wave-private LDS P buffer
// (C-layout -> A-layout); no max-shift; l via ones-MFMA; no barriers.
__global__ __launch_bounds__(256) void attn_kernel(
        const unsigned short* __restrict__ kq,   // [b*s][h*128 + (q|k)]
        const unsigned short* __restrict__ vT,   // [b][h][d][s]
        unsigned short* __restrict__ attn_out) { // [b][s][512]
    int i = blockIdx.x;
    int xcd = i & 7, slot = i >> 3;              // slot 0..127
    int bh = xcd * 8 + (slot >> 4);              // 8 (b,h) pairs per XCD
    int qt = slot & 15;
    int b = bh >> 3, h = bh & 7;

    int t = threadIdx.x;
    int wid = t >> 6, lane = t & 63, quad = lane >> 4, l16 = lane & 15;
    int q0 = qt * 64 + wid * 16;

    __shared__ unsigned short ldsP[4][16 * 40];  // wave-private: 16 q-rows x 32 keys

    // Q A-fragment: A[m=q=l16][k=d=quad*8+j]
    const unsigned short* qrow = kq + ((size_t)b * S_ + q0 + l16) * 1024 + h * 128;
    frag8 qf0 = *(const frag8*)(qrow + quad * 8);
    frag8 qf1 = *(const frag8*)(qrow + 32 + quad * 8);

    frag8 ones;
    for (int i2 = 0; i2 < 8; ++i2) ones[i2] = (short)0x3f80;   // bf16 1.0

    f32x4 o[4], ol;
    ol = zero4();
    for (int dt = 0; dt < 4; ++dt) o[dt] = zero4();

    const unsigned short* kbase = kq + (size_t)b * S_ * 1024 + h * 128 + 64;
    const unsigned short* vbase = vT + ((size_t)b * NH + h) * HD * S_;
    unsigned short* pw = &ldsP[wid][0];

    // K B-fragment ping-pong: B[n=key][k=d], key tiles {l16, 16+l16}
    frag8 kf[2][4];
    {
        const unsigned short* kr = kbase + (size_t)l16 * 1024 + quad * 8;
        kf[0][0] = *(const frag8*)(kr);
        kf[0][1] = *(const frag8*)(kr + 32);
        kf[0][2] = *(const frag8*)(kr + 16 * 1024);
        kf[0][3] = *(const frag8*)(kr + 16 * 1024 + 32);
    }

    #pragma unroll 2
    for (int it = 0; it < S_ / 32; ++it) {
        int j0 = it * 32;
        int cur = it & 1, nxt = cur ^ 1;

        if (it < S_ / 32 - 1) {
            const unsigned short* kr = kbase + (size_t)(j0 + 32 + l16) * 1024 + quad * 8;
            kf[nxt][0] = *(const frag8*)(kr);
            kf[nxt][1] = *(const frag8*)(kr + 32);
            kf[nxt][2] = *(const frag8*)(kr + 16 * 1024);
            kf[nxt][3] = *(const frag8*)(kr + 16 * 1024 + 32);
        }

        // V^T B-frags for PV (issued early, consumed after exp):
        // B[n=d rel][k=key=quad*8+j]
        frag8 vf[4];
        for (int dt = 0; dt < 4; ++dt)
            vf[dt] = *(const frag8*)(vbase + (size_t)(dt * 16 + l16) * S_ + j0 + quad * 8);

        // S = Qs @ K^T  (C-layout: row=q=quad*4+r, col=key=ni*16+l16)
        f32x4 s0 = zero4(), s1 = zero4();
        s0 = __builtin_amdgcn_mfma_f32_16x16x32_bf16(qf0, kf[cur][0], s0, 0, 0, 0);
        s0 = __builtin_amdgcn_mfma_f32_16x16x32_bf16(qf1, kf[cur][1], s0, 0, 0, 0);
        s1 = __builtin_amdgcn_mfma_f32_16x16x32_bf16(qf0, kf[cur][2], s1, 0, 0, 0);
        s1 = __builtin_amdgcn_mfma_f32_16x16x32_bf16(qf1, kf[cur][3], s1, 0, 0, 0);

        // P = exp(S) -> LDS (C-layout -> A-layout, wave-private, no barrier)
        for (int r = 0; r < 4; ++r) {
            pw[(quad * 4 + r) * 40 + l16]      = f2bf(__expf(s0[r]));
            pw[(quad * 4 + r) * 40 + 16 + l16] = f2bf(__expf(s1[r]));
        }
        frag8 pf = *(const frag8*)(&pw[l16 * 40 + quad * 8]);

        // PV: o[dt] += P(A) * V^T(B); l += P * ones
        ol = __builtin_amdgcn_mfma_f32_16x16x32_bf16(pf, ones, ol, 0, 0, 0);
        for (int dt = 0; dt < 4; ++dt)
            o[dt] = __builtin_amdgcn_mfma_f32_16x16x32_bf16(pf, vf[dt], o[dt], 0, 0, 0);
    }

    // O C-layout: lane(quad,l16) holds O[q=quad*4+r][d=dt*16+l16]; ol same rows
    for (int r = 0; r < 4; ++r) {
        float inv = 1.0f / ol[r];
        int qrw = q0 + quad * 4 + r;
        for (int dt = 0; dt < 4; ++dt) {
            int ch = h * HD + dt * 16 + l16;
            attn_out[((size_t)b * S_ + qrw) * C_ + ch] = f2bf(o[dt][r] * inv);
        }
    }
}

// ---------------------------------------------------------------- launch
extern "C" void kernel_launch(void* const* d_in, const int* in_sizes, int n_in,
                              void* d_out, int out_size, void* d_ws, size_t ws_size,
                              hipStream_t stream) {
    const float* x        = (const float*)d_in[0];
    const float* gn_scale = (const float*)d_in[2];
    const float* gn_bias  = (const float*)d_in[3];
    const float* w_qkv    = (const float*)d_in[4];
    const float* b_qkv    = (const float*)d_in[5];
    const float* w_out    = (const float*)d_in[6];
    const float* b_out    = (const float*)d_in[7];
    float* out = (float*)d_out;

    char* ws = (char*)d_ws;
    unsigned short* xn    = (unsigned short*)(ws);                          // 8 MB
    unsigned short* kq    = (unsigned short*)(ws + ((size_t)8  << 20));     // 16 MB
    unsigned short* attn  = (unsigned short*)(ws + ((size_t)24 << 20));     // 8 MB
    unsigned short* vT    = (unsigned short*)(ws + ((size_t)32 << 20));     // 8 MB
    unsigned short* wqkvT = (unsigned short*)(ws + ((size_t)40 << 20));     // 1.5 MB
    unsigned short* woutT = (unsigned short*)(ws + ((size_t)40 << 20) + ((size_t)3 << 19)); // 0.5 MB

    transpose_kernel<<<dim3(QKVC / 32, C_ / 32), 256, 0, stream>>>(w_qkv, wqkvT, C_, QKVC);
    transpose_kernel<<<dim3(C_ / 32, C_ / 32), 256, 0, stream>>>(w_out, woutT, C_, C_);

    gn_kernel<<<dim3(B_ * GROUPS), 256, 0, stream>>>(x, gn_scale, gn_bias, xn);

    gemm_kernel<0><<<dim3(QKVC / 128, (B_ * S_) / 128), 256, 0, stream>>>(
        xn, wqkvT, b_qkv, nullptr, kq, vT, nullptr, B_ * S_, QKVC, C_);

    attn_kernel<<<dim3(1024), 256, 0, stream>>>(kq, vT, attn);

    gemm_kernel<1><<<dim3(C_ / 128, (B_ * S_) / 128), 256, 0, stream>>>(
        attn, woutT, b_out, xn, nullptr, nullptr, out, B_ * S_, C_, C_);
}

// Round 8
// 178.702 us; speedup vs baseline: 1.8928x; 1.5913x over previous
//
#include <hip/hip_runtime.h>
#include <hip/hip_bf16.h>

// AttentionBlock: GroupNorm -> QKV -> MHA (8 heads, hd=64, s=1024) -> out proj -> +xn
// Inputs/outputs FP32; internally bf16 for MFMA.
//
// r8 insight: attention r4/r5/r7 were L2-request-bound on 64-line scattered
// fragment gathers (model matches all three timings). Fix: block-stage K/V
// tiles into LDS via global_load_lds (coalesced lines, linear LDS mapping),
// double-buffered; GEMMs stage B tiles through LDS too (m97 structure).
//
// ws: xn 8MB @0 | kq 16MB @8 | attn 8MB @24 | vT 8MB @32 | wqkvT 1.5MB @40 | woutT .5MB @41.5

#define B_    8
#define S_    1024
#define C_    512
#define NH    8
#define HD    64
#define QKVC  1536
#define GROUPS 32
#define GSIZE  16
#define EPSV   1e-5f

using frag8 = __attribute__((ext_vector_type(8))) short;   // 8 bf16 = 4 VGPR
using f32x4 = __attribute__((ext_vector_type(4))) float;

__device__ __forceinline__ float bf2f(unsigned short u) {
    union { unsigned int i; float f; } v; v.i = ((unsigned int)u) << 16; return v.f;
}
__device__ __forceinline__ unsigned short f2bf(float f) {
    union { float f; unsigned int i; } v; v.f = f;
    unsigned int x = v.i;
    return (unsigned short)((x + 0x7fffu + ((x >> 16) & 1u)) >> 16);
}
__device__ __forceinline__ f32x4 zero4() {
    f32x4 z; z[0] = 0.f; z[1] = 0.f; z[2] = 0.f; z[3] = 0.f; return z;
}
__device__ __forceinline__ void gl_lds(const unsigned short* gp, unsigned short* lp) {
    __builtin_amdgcn_global_load_lds(
        (const __attribute__((address_space(1))) void*)gp,
        (__attribute__((address_space(3))) void*)lp, 16, 0, 0);
}

// ---------------------------------------------------------------- transpose
__global__ __launch_bounds__(256) void transpose_kernel(
        const float* __restrict__ in, unsigned short* __restrict__ out,
        int K, int N) {
    __shared__ float tile[32][33];
    int n0 = blockIdx.x * 32, k0 = blockIdx.y * 32;
    int t = threadIdx.x;
    for (int i = 0; i < 4; ++i) {
        int idx = t + i * 256; int r = idx >> 5, c = idx & 31;
        tile[r][c] = in[(size_t)(k0 + r) * N + n0 + c];
    }
    __syncthreads();
    for (int i = 0; i < 4; ++i) {
        int idx = t + i * 256; int r = idx >> 5, c = idx & 31;
        out[(size_t)(n0 + r) * K + k0 + c] = f2bf(tile[c][r]);
    }
}

// ---------------------------------------------------------------- groupnorm
// (r4 version — proven passing; r6's register-cached variant crashed)
__global__ __launch_bounds__(256) void gn_kernel(
        const float* __restrict__ x,
        const float* __restrict__ scale,
        const float* __restrict__ bias,
        unsigned short* __restrict__ xn) {
    int bg = blockIdx.x;
    int b = bg >> 5, g = bg & 31;
    const float* xb = x + (size_t)b * S_ * C_;
    int t = threadIdx.x;

    float sum = 0.f, ss = 0.f;
    for (int i = 0; i < 16; ++i) {
        int idx = t + i * 256;
        int row = idx >> 2, j = idx & 3;
        float4 v = *(const float4*)(xb + (size_t)row * C_ + g * GSIZE + j * 4);
        sum += v.x + v.y + v.z + v.w;
        ss  += v.x * v.x + v.y * v.y + v.z * v.z + v.w * v.w;
    }
    for (int off = 1; off < 64; off <<= 1) {
        sum += __shfl_xor(sum, off);
        ss  += __shfl_xor(ss,  off);
    }
    __shared__ float s_sum[4], s_ss[4];
    int wid = t >> 6;
    if ((t & 63) == 0) { s_sum[wid] = sum; s_ss[wid] = ss; }
    __syncthreads();
    sum = s_sum[0] + s_sum[1] + s_sum[2] + s_sum[3];
    ss  = s_ss[0]  + s_ss[1]  + s_ss[2]  + s_ss[3];
    float mean = sum * (1.f / 16384.f);
    float var  = ss * (1.f / 16384.f) - mean * mean;
    float rinv = rsqrtf(var + EPSV);

    float sc[16], bi[16];
    for (int u = 0; u < 16; ++u) {
        sc[u] = scale[g * GSIZE + u];
        bi[u] = bias[g * GSIZE + u];
    }
    for (int i = 0; i < 16; ++i) {
        int idx = t + i * 256;
        int row = idx >> 2, j = idx & 3;
        float4 v = *(const float4*)(xb + (size_t)row * C_ + g * GSIZE + j * 4);
        int c0 = j * 4;
        float f0 = (v.x - mean) * rinv * sc[c0 + 0] + bi[c0 + 0];
        float f1 = (v.y - mean) * rinv * sc[c0 + 1] + bi[c0 + 1];
        float f2 = (v.z - mean) * rinv * sc[c0 + 2] + bi[c0 + 2];
        float f3 = (v.w - mean) * rinv * sc[c0 + 3] + bi[c0 + 3];
        uint2 o;
        o.x = (unsigned int)f2bf(f0) | ((unsigned int)f2bf(f1) << 16);
        o.y = (unsigned int)f2bf(f2) | ((unsigned int)f2bf(f3) << 16);
        *(uint2*)(xn + (size_t)b * S_ * C_ + (size_t)row * C_ + g * GSIZE + c0) = o;
    }
}

// ---------------------------------------------------------------- GEMM
// 128x128 tile, 4 waves x 64x64, BK=32, A AND B staged via global_load_lds
// w=16 (m97 structure). MODE 0: qkv epilogue. MODE 1: fp32 out + bf16 resid.
template<int MODE>
__global__ __launch_bounds__(256) void gemm_kernel(
        const unsigned short* __restrict__ A,
        const unsigned short* __restrict__ Bt,
        const float* __restrict__ bias,
        const unsigned short* __restrict__ resid,
        unsigned short* __restrict__ outA,   // MODE0: kq [M][1024]
        unsigned short* __restrict__ outV,   // MODE0: vT [b][h][64][1024]
        float* __restrict__ outF,            // MODE1: fp32 [M][N]
        int M, int N, int K) {
    __shared__ unsigned short As[128 * 32];
    __shared__ unsigned short Bs[128 * 32];
    int m0 = blockIdx.y * 128, n0 = blockIdx.x * 128;
    int t = threadIdx.x;
    int wid = t >> 6, lane = t & 63;
    int quad = lane >> 4, l16 = lane & 15;
    int wm = (wid >> 1) * 64, wn = (wid & 1) * 64;

    f32x4 acc[4][4];
    for (int mi = 0; mi < 4; ++mi)
        for (int ni = 0; ni < 4; ++ni) acc[mi][ni] = zero4();

    for (int k0 = 0; k0 < K; k0 += 32) {
        __syncthreads();
        for (int i = 0; i < 2; ++i) {
            int idx = i * 256 + t;                 // 0..511 16B slots
            int row = idx >> 2, seg = idx & 3;
            gl_lds(A + (size_t)(m0 + row) * K + k0 + seg * 8,
                   As + (size_t)(i * 256 + wid * 64) * 8);
            gl_lds(Bt + (size_t)(n0 + row) * K + k0 + seg * 8,
                   Bs + (size_t)(i * 256 + wid * 64) * 8);
        }
        __syncthreads();

        frag8 bfrag[4], afrag[4];
        for (int ni = 0; ni < 4; ++ni)
            bfrag[ni] = *(const frag8*)(&Bs[(wn + ni * 16 + l16) * 32 + quad * 8]);
        for (int mi = 0; mi < 4; ++mi)
            afrag[mi] = *(const frag8*)(&As[(wm + mi * 16 + l16) * 32 + quad * 8]);

        for (int mi = 0; mi < 4; ++mi)
            for (int ni = 0; ni < 4; ++ni)
                acc[mi][ni] = __builtin_amdgcn_mfma_f32_16x16x32_bf16(
                    afrag[mi], bfrag[ni], acc[mi][ni], 0, 0, 0);
    }

    for (int ni = 0; ni < 4; ++ni) {
        int c0 = n0 + wn + ni * 16;                 // tile base col (multiple of 16)
        float bv = bias[c0 + l16];
        if (MODE == 0) {
            int h = c0 / 192, rr = c0 % 192;        // section uniform per tile
            if (rr >= 128) {
                // V -> vT[b][h][d][s], packed ushort4 along s (r contiguous)
                int d = rr - 128 + l16;
                int bidx = m0 >> 10;
                unsigned short* vp = outV + (((size_t)bidx * NH + h) * HD + d) * S_
                                   + (m0 & 1023) + wm + quad * 4;
                for (int mi = 0; mi < 4; ++mi) {
                    ushort4 pk;
                    pk.x = f2bf(acc[mi][ni][0] + bv);
                    pk.y = f2bf(acc[mi][ni][1] + bv);
                    pk.z = f2bf(acc[mi][ni][2] + bv);
                    pk.w = f2bf(acc[mi][ni][3] + bv);
                    *(ushort4*)(vp + mi * 16) = pk;
                }
            } else {
                float scl = (rr < 64) ? 0.125f : 1.0f;
                int colk = h * 128 + rr + l16;
                for (int mi = 0; mi < 4; ++mi)
                    for (int r = 0; r < 4; ++r) {
                        int row = m0 + wm + mi * 16 + quad * 4 + r;
                        outA[(size_t)row * 1024 + colk] = f2bf((acc[mi][ni][r] + bv) * scl);
                    }
            }
        } else {
            int col = c0 + l16;
            for (int mi = 0; mi < 4; ++mi)
                for (int r = 0; r < 4; ++r) {
                    int row = m0 + wm + mi * 16 + quad * 4 + r;
                    float v = acc[mi][ni][r] + bv + bf2f(resid[(size_t)row * N + col]);
                    outF[(size_t)row * N + col] = v;
                }
        }
    }
}

// ---------------------------------------------------------------- attention
// 512 blocks (XCD-swizzled), 4 waves x 32 q-rows, 32 keys/iter.
// K/V tiles block-staged into LDS via global_load_lds (coalesced, double-
// buffered, 1 barrier/iter). Frag reads are m97-style stride-32 LDS b128.
// No max-shift; l via ones-MFMA; P through wave-private LDS (stride 40).
__global__ __launch_bounds__(256) void attn_kernel(
        const unsigned short* __restrict__ kq,   // [b*s][h*128 + (q|k)]
        const unsigned short* __restrict__ vT,   // [b][h][d][s]
        unsigned short* __restrict__ attn_out) { // [b][s][512]
    int i = blockIdx.x;
    int xcd = i & 7, slot = i >> 3;              // slot 0..63
    int bh = xcd * 8 + (slot >> 3);              // 8 (b,h) pairs per XCD
    int qt = slot & 7;
    int b = bh >> 3, h = bh & 7;

    int t = threadIdx.x;
    int wid = t >> 6, lane = t & 63, quad = lane >> 4, l16 = lane & 15;
    int q0 = qt * 128 + wid * 32;

    // LDS: K tile [dh][key32][d32] stride 32, V tile [d64][key32] stride 32
    __shared__ unsigned short Ks[2][2048];       // 2 x 4KB
    __shared__ unsigned short Vs[2][2048];       // 2 x 4KB
    __shared__ unsigned short Ps[4][32 * 40];    // wave-private P (32q x 32k)

    // Q A-fragments: A[m=q][k=d] (one-time scattered load, prologue only)
    frag8 qf[2][2];
    for (int mi = 0; mi < 2; ++mi) {
        const unsigned short* qrow = kq + ((size_t)b * S_ + q0 + mi * 16 + l16) * 1024 + h * 128;
        qf[mi][0] = *(const frag8*)(qrow + quad * 8);
        qf[mi][1] = *(const frag8*)(qrow + 32 + quad * 8);
    }
    frag8 ones;
    for (int i2 = 0; i2 < 8; ++i2) ones[i2] = (short)0x3f80;   // bf16 1.0

    f32x4 o[2][4], ol[2];
    for (int mi = 0; mi < 2; ++mi) {
        ol[mi] = zero4();
        for (int dt = 0; dt < 4; ++dt) o[mi][dt] = zero4();
    }

    const unsigned short* kbase = kq + (size_t)b * S_ * 1024 + h * 128 + 64;
    const unsigned short* vbase = vT + ((size_t)b * NH + h) * HD * S_;
    unsigned short* pw = &Ps[wid][0];

    // staging lane roles (wave-uniform LDS bases; per-lane global addrs)
    int kdh = wid & 1, krh = wid >> 1;           // K: wave -> (d-half, key-half)
    int krow = krh * 16 + (lane >> 2);           // key row 0..31
    int kseg = lane & 3;                         // d segment within half
    int vd = wid * 16 + (lane >> 2);             // V: d row 0..63
    int vseg = lane & 3;                         // key segment

    auto stage = [&](int j0, int buf) {
        gl_lds(kbase + (size_t)(j0 + krow) * 1024 + kdh * 32 + kseg * 8,
               &Ks[buf][kdh * 1024 + krh * 512]);
        gl_lds(vbase + (size_t)vd * S_ + j0 + vseg * 8,
               &Vs[buf][wid * 512]);
    };

    stage(0, 0);

    for (int it = 0; it < S_ / 32; ++it) {
        int cur = it & 1, nxt = cur ^ 1;
        __syncthreads();                          // staging of cur complete
        if (it < S_ / 32 - 1) stage((it + 1) * 32, nxt);

        // K B-frags from LDS: B[n=key][k=d]  (stride-32 m97 pattern)
        frag8 kf[2][2];
        for (int kh = 0; kh < 2; ++kh)
            for (int dh = 0; dh < 2; ++dh)
                kf[kh][dh] = *(const frag8*)(&Ks[cur][dh * 1024 + (kh * 16 + l16) * 32 + quad * 8]);

        // S = Qs @ K^T  (C-layout: row=q=quad*4+r, col=key=kh*16+l16)
        f32x4 s[2][2];
        for (int mi = 0; mi < 2; ++mi)
            for (int kh = 0; kh < 2; ++kh) {
                f32x4 acc = zero4();
                acc = __builtin_amdgcn_mfma_f32_16x16x32_bf16(qf[mi][0], kf[kh][0], acc, 0, 0, 0);
                acc = __builtin_amdgcn_mfma_f32_16x16x32_bf16(qf[mi][1], kf[kh][1], acc, 0, 0, 0);
                s[mi][kh] = acc;
            }

        // P = exp(S) -> wave-private LDS (C-layout -> A-layout)
        for (int mi = 0; mi < 2; ++mi)
            for (int kh = 0; kh < 2; ++kh)
                for (int r = 0; r < 4; ++r)
                    pw[(mi * 16 + quad * 4 + r) * 40 + kh * 16 + l16] = f2bf(__expf(s[mi][kh][r]));

        frag8 pf[2];
        pf[0] = *(const frag8*)(&pw[l16 * 40 + quad * 8]);
        pf[1] = *(const frag8*)(&pw[(16 + l16) * 40 + quad * 8]);

        // V B-frags from LDS: B[n=d][k=key]
        frag8 vf[4];
        for (int dt = 0; dt < 4; ++dt)
            vf[dt] = *(const frag8*)(&Vs[cur][(dt * 16 + l16) * 32 + quad * 8]);

        for (int mi = 0; mi < 2; ++mi) {
            ol[mi] = __builtin_amdgcn_mfma_f32_16x16x32_bf16(pf[mi], ones, ol[mi], 0, 0, 0);
            for (int dt = 0; dt < 4; ++dt)
                o[mi][dt] = __builtin_amdgcn_mfma_f32_16x16x32_bf16(pf[mi], vf[dt], o[mi][dt], 0, 0, 0);
        }
    }

    for (int mi = 0; mi < 2; ++mi)
        for (int r = 0; r < 4; ++r) {
            float inv = 1.0f / ol[mi][r];
            int qrw = q0 + mi * 16 + quad * 4 + r;
            for (int dt = 0; dt < 4; ++dt) {
                int ch = h * HD + dt * 16 + l16;
                attn_out[((size_t)b * S_ + qrw) * C_ + ch] = f2bf(o[mi][dt][r] * inv);
            }
        }
}

// ---------------------------------------------------------------- launch
extern "C" void kernel_launch(void* const* d_in, const int* in_sizes, int n_in,
                              void* d_out, int out_size, void* d_ws, size_t ws_size,
                              hipStream_t stream) {
    const float* x        = (const float*)d_in[0];
    const float* gn_scale = (const float*)d_in[2];
    const float* gn_bias  = (const float*)d_in[3];
    const float* w_qkv    = (const float*)d_in[4];
    const float* b_qkv    = (const float*)d_in[5];
    const float* w_out    = (const float*)d_in[6];
    const float* b_out    = (const float*)d_in[7];
    float* out = (float*)d_out;

    char* ws = (char*)d_ws;
    unsigned short* xn    = (unsigned short*)(ws);                          // 8 MB
    unsigned short* kq    = (unsigned short*)(ws + ((size_t)8  << 20));     // 16 MB
    unsigned short* attn  = (unsigned short*)(ws + ((size_t)24 << 20));     // 8 MB
    unsigned short* vT    = (unsigned short*)(ws + ((size_t)32 << 20));     // 8 MB
    unsigned short* wqkvT = (unsigned short*)(ws + ((size_t)40 << 20));     // 1.5 MB
    unsigned short* woutT = (unsigned short*)(ws + ((size_t)40 << 20) + ((size_t)3 << 19)); // 0.5 MB

    transpose_kernel<<<dim3(QKVC / 32, C_ / 32), 256, 0, stream>>>(w_qkv, wqkvT, C_, QKVC);
    transpose_kernel<<<dim3(C_ / 32, C_ / 32), 256, 0, stream>>>(w_out, woutT, C_, C_);

    gn_kernel<<<dim3(B_ * GROUPS), 256, 0, stream>>>(x, gn_scale, gn_bias, xn);

    gemm_kernel<0><<<dim3(QKVC / 128, (B_ * S_) / 128), 256, 0, stream>>>(
        xn, wqkvT, b_qkv, nullptr, kq, vT, nullptr, B_ * S_, QKVC, C_);

    attn_kernel<<<dim3(512), 256, 0, stream>>>(kq, vT, attn);

    gemm_kernel<1><<<dim3(C_ / 128, (B_ * S_) / 128), 256, 0, stream>>>(
        attn, woutT, b_out, xn, nullptr, nullptr, out, B_ * S_, C_, C_);
}

// Round 9
// 170.733 us; speedup vs baseline: 1.9811x; 1.0467x over previous
//
#include <hip/hip_runtime.h>
#include <hip/hip_bf16.h>

// AttentionBlock: GroupNorm -> QKV -> MHA (8 heads, hd=64, s=1024) -> out proj -> +xn
// Inputs/outputs FP32; internally bf16 for MFMA.
//
// r9: attn was VALU-bound (manual RNE f2bf ~6 ops/val) + P-write bank
// conflicts (4-way). Fixes: (1) fold log2e into q-scale so P=v_exp(S) is one
// instr; (2) compute S^T so the 4 C-regs are row-contiguous in P[q][key] ->
// pack via v_perm_b32, one ds_write_b64 per tile (was 16 b16, ~4-way);
// (3) GEMM K-loop double-buffered, 1 barrier/iter.
//
// ws: xn 8MB @0 | kq 16MB @8 | attn 8MB @24 | vT 8MB @32 | wqkvT 1.5MB @40 | woutT .5MB @41.5

#define B_    8
#define S_    1024
#define C_    512
#define NH    8
#define HD    64
#define QKVC  1536
#define GROUPS 32
#define GSIZE  16
#define EPSV   1e-5f
#define QSCL  0.18033688f   // 0.125 * log2(e)

using frag8 = __attribute__((ext_vector_type(8))) short;   // 8 bf16 = 4 VGPR
using f32x4 = __attribute__((ext_vector_type(4))) float;

__device__ __forceinline__ float bf2f(unsigned short u) {
    union { unsigned int i; float f; } v; v.i = ((unsigned int)u) << 16; return v.f;
}
__device__ __forceinline__ unsigned short f2bf(float f) {
    union { float f; unsigned int i; } v; v.f = f;
    unsigned int x = v.i;
    return (unsigned short)((x + 0x7fffu + ((x >> 16) & 1u)) >> 16);
}
// pack two fp32 -> two bf16 (round-half-up) in one dword: 2 adds + 1 v_perm
__device__ __forceinline__ unsigned int pk2bf(float a, float b) {
    union { float f; unsigned int u; } x, y; x.f = a; y.f = b;
    return __builtin_amdgcn_perm(y.u + 0x8000u, x.u + 0x8000u, 0x07060302u);
}
__device__ __forceinline__ float fexp2(float x) {
#if __has_builtin(__builtin_amdgcn_exp2f)
    return __builtin_amdgcn_exp2f(x);
#else
    return exp2f(x);
#endif
}
__device__ __forceinline__ f32x4 zero4() {
    f32x4 z; z[0] = 0.f; z[1] = 0.f; z[2] = 0.f; z[3] = 0.f; return z;
}
__device__ __forceinline__ void gl_lds(const unsigned short* gp, unsigned short* lp) {
    __builtin_amdgcn_global_load_lds(
        (const __attribute__((address_space(1))) void*)gp,
        (__attribute__((address_space(3))) void*)lp, 16, 0, 0);
}

// ---------------------------------------------------------------- transpose
__global__ __launch_bounds__(256) void transpose_kernel(
        const float* __restrict__ in, unsigned short* __restrict__ out,
        int K, int N) {
    __shared__ float tile[32][33];
    int n0 = blockIdx.x * 32, k0 = blockIdx.y * 32;
    int t = threadIdx.x;
    for (int i = 0; i < 4; ++i) {
        int idx = t + i * 256; int r = idx >> 5, c = idx & 31;
        tile[r][c] = in[(size_t)(k0 + r) * N + n0 + c];
    }
    __syncthreads();
    for (int i = 0; i < 4; ++i) {
        int idx = t + i * 256; int r = idx >> 5, c = idx & 31;
        out[(size_t)(n0 + r) * K + k0 + c] = f2bf(tile[c][r]);
    }
}

// ---------------------------------------------------------------- groupnorm
// (r4 version — proven passing; r6's register-cached variant crashed)
__global__ __launch_bounds__(256) void gn_kernel(
        const float* __restrict__ x,
        const float* __restrict__ scale,
        const float* __restrict__ bias,
        unsigned short* __restrict__ xn) {
    int bg = blockIdx.x;
    int b = bg >> 5, g = bg & 31;
    const float* xb = x + (size_t)b * S_ * C_;
    int t = threadIdx.x;

    float sum = 0.f, ss = 0.f;
    for (int i = 0; i < 16; ++i) {
        int idx = t + i * 256;
        int row = idx >> 2, j = idx & 3;
        float4 v = *(const float4*)(xb + (size_t)row * C_ + g * GSIZE + j * 4);
        sum += v.x + v.y + v.z + v.w;
        ss  += v.x * v.x + v.y * v.y + v.z * v.z + v.w * v.w;
    }
    for (int off = 1; off < 64; off <<= 1) {
        sum += __shfl_xor(sum, off);
        ss  += __shfl_xor(ss,  off);
    }
    __shared__ float s_sum[4], s_ss[4];
    int wid = t >> 6;
    if ((t & 63) == 0) { s_sum[wid] = sum; s_ss[wid] = ss; }
    __syncthreads();
    sum = s_sum[0] + s_sum[1] + s_sum[2] + s_sum[3];
    ss  = s_ss[0]  + s_ss[1]  + s_ss[2]  + s_ss[3];
    float mean = sum * (1.f / 16384.f);
    float var  = ss * (1.f / 16384.f) - mean * mean;
    float rinv = rsqrtf(var + EPSV);

    float sc[16], bi[16];
    for (int u = 0; u < 16; ++u) {
        sc[u] = scale[g * GSIZE + u];
        bi[u] = bias[g * GSIZE + u];
    }
    for (int i = 0; i < 16; ++i) {
        int idx = t + i * 256;
        int row = idx >> 2, j = idx & 3;
        float4 v = *(const float4*)(xb + (size_t)row * C_ + g * GSIZE + j * 4);
        int c0 = j * 4;
        float f0 = (v.x - mean) * rinv * sc[c0 + 0] + bi[c0 + 0];
        float f1 = (v.y - mean) * rinv * sc[c0 + 1] + bi[c0 + 1];
        float f2 = (v.z - mean) * rinv * sc[c0 + 2] + bi[c0 + 2];
        float f3 = (v.w - mean) * rinv * sc[c0 + 3] + bi[c0 + 3];
        uint2 o;
        o.x = (unsigned int)f2bf(f0) | ((unsigned int)f2bf(f1) << 16);
        o.y = (unsigned int)f2bf(f2) | ((unsigned int)f2bf(f3) << 16);
        *(uint2*)(xn + (size_t)b * S_ * C_ + (size_t)row * C_ + g * GSIZE + c0) = o;
    }
}

// ---------------------------------------------------------------- GEMM
// 128x128 tile, 4 waves x 64x64, BK=32, A+B staged via global_load_lds w=16,
// double-buffered (1 barrier/iter). MODE 0: qkv epilogue. MODE 1: fp32+resid.
template<int MODE>
__global__ __launch_bounds__(256) void gemm_kernel(
        const unsigned short* __restrict__ A,
        const unsigned short* __restrict__ Bt,
        const float* __restrict__ bias,
        const unsigned short* __restrict__ resid,
        unsigned short* __restrict__ outA,   // MODE0: kq [M][1024]
        unsigned short* __restrict__ outV,   // MODE0: vT [b][h][64][1024]
        float* __restrict__ outF,            // MODE1: fp32 [M][N]
        int M, int N, int K) {
    __shared__ unsigned short As[2][128 * 32];
    __shared__ unsigned short Bs[2][128 * 32];
    int m0 = blockIdx.y * 128, n0 = blockIdx.x * 128;
    int t = threadIdx.x;
    int wid = t >> 6, lane = t & 63;
    int quad = lane >> 4, l16 = lane & 15;
    int wm = (wid >> 1) * 64, wn = (wid & 1) * 64;

    f32x4 acc[4][4];
    for (int mi = 0; mi < 4; ++mi)
        for (int ni = 0; ni < 4; ++ni) acc[mi][ni] = zero4();

    int srow = t >> 2, sseg = t & 3;             // staging roles
    auto stage = [&](int k0, int buf) {
        for (int i = 0; i < 2; ++i) {
            gl_lds(A + (size_t)(m0 + i * 64 + srow) * K + k0 + sseg * 8,
                   &As[buf][(size_t)(i * 256 + wid * 64) * 8]);
            gl_lds(Bt + (size_t)(n0 + i * 64 + srow) * K + k0 + sseg * 8,
                   &Bs[buf][(size_t)(i * 256 + wid * 64) * 8]);
        }
    };

    stage(0, 0);
    int nk = K >> 5;
    for (int i = 0; i < nk; ++i) {
        __syncthreads();                         // buf i&1 staged; prev reads done
        if (i + 1 < nk) stage((i + 1) << 5, (i + 1) & 1);
        int buf = i & 1;

        frag8 bfrag[4], afrag[4];
        for (int ni = 0; ni < 4; ++ni)
            bfrag[ni] = *(const frag8*)(&Bs[buf][(wn + ni * 16 + l16) * 32 + quad * 8]);
        for (int mi = 0; mi < 4; ++mi)
            afrag[mi] = *(const frag8*)(&As[buf][(wm + mi * 16 + l16) * 32 + quad * 8]);

        for (int mi = 0; mi < 4; ++mi)
            for (int ni = 0; ni < 4; ++ni)
                acc[mi][ni] = __builtin_amdgcn_mfma_f32_16x16x32_bf16(
                    afrag[mi], bfrag[ni], acc[mi][ni], 0, 0, 0);
    }

    for (int ni = 0; ni < 4; ++ni) {
        int c0 = n0 + wn + ni * 16;                 // tile base col (multiple of 16)
        float bv = bias[c0 + l16];
        if (MODE == 0) {
            int h = c0 / 192, rr = c0 % 192;        // section uniform per tile
            if (rr >= 128) {
                // V -> vT[b][h][d][s], packed 4 bf16 along s (r contiguous)
                int d = rr - 128 + l16;
                int bidx = m0 >> 10;
                unsigned short* vp = outV + (((size_t)bidx * NH + h) * HD + d) * S_
                                   + (m0 & 1023) + wm + quad * 4;
                for (int mi = 0; mi < 4; ++mi) {
                    uint2 pk;
                    pk.x = pk2bf(acc[mi][ni][0] + bv, acc[mi][ni][1] + bv);
                    pk.y = pk2bf(acc[mi][ni][2] + bv, acc[mi][ni][3] + bv);
                    *(uint2*)(vp + mi * 16) = pk;
                }
            } else {
                float scl = (rr < 64) ? QSCL : 1.0f;   // q pre-scaled by log2e/8
                int colk = h * 128 + rr + l16;
                for (int mi = 0; mi < 4; ++mi)
                    for (int r = 0; r < 4; ++r) {
                        int row = m0 + wm + mi * 16 + quad * 4 + r;
                        outA[(size_t)row * 1024 + colk] = f2bf((acc[mi][ni][r] + bv) * scl);
                    }
            }
        } else {
            int col = c0 + l16;
            for (int mi = 0; mi < 4; ++mi)
                for (int r = 0; r < 4; ++r) {
                    int row = m0 + wm + mi * 16 + quad * 4 + r;
                    float v = acc[mi][ni][r] + bv + bf2f(resid[(size_t)row * N + col]);
                    outF[(size_t)row * N + col] = v;
                }
        }
    }
}

// ---------------------------------------------------------------- attention
// 512 blocks (XCD-swizzled), 4 waves x 32 q-rows, 32 keys/iter.
// K/V LDS-staged (double-buffered, 1 barrier/iter). S^T = K@Q^T so the four
// C-regs per (mi,kh) are row-contiguous in P[q][key]: pack 4 bf16 (v_perm) ->
// one ds_write_b64. P = v_exp(S) directly (q pre-scaled by log2e/8).
__global__ __launch_bounds__(256) void attn_kernel(
        const unsigned short* __restrict__ kq,   // [b*s][h*128 + (q|k)]
        const unsigned short* __restrict__ vT,   // [b][h][d][s]
        unsigned short* __restrict__ attn_out) { // [b][s][512]
    int i = blockIdx.x;
    int xcd = i & 7, slot = i >> 3;              // slot 0..63
    int bh = xcd * 8 + (slot >> 3);              // 8 (b,h) pairs per XCD
    int qt = slot & 7;
    int b = bh >> 3, h = bh & 7;

    int t = threadIdx.x;
    int wid = t >> 6, lane = t & 63, quad = lane >> 4, l16 = lane & 15;
    int q0 = qt * 128 + wid * 32;

    __shared__ unsigned short Ks[2][2048];       // K tile [dh][key32][d32]
    __shared__ unsigned short Vs[2][2048];       // V tile [d64][key32]
    __shared__ unsigned short Ps[4][32 * 40];    // wave-private P[q32][key32]

    // Q B-fragments: B[n=q][k=d] (one-time scattered load, prologue only)
    frag8 qf[2][2];
    for (int mi = 0; mi < 2; ++mi) {
        const unsigned short* qrow = kq + ((size_t)b * S_ + q0 + mi * 16 + l16) * 1024 + h * 128;
        qf[mi][0] = *(const frag8*)(qrow + quad * 8);
        qf[mi][1] = *(const frag8*)(qrow + 32 + quad * 8);
    }
    frag8 ones;
    for (int i2 = 0; i2 < 8; ++i2) ones[i2] = (short)0x3f80;   // bf16 1.0

    f32x4 o[2][4], ol[2];
    for (int mi = 0; mi < 2; ++mi) {
        ol[mi] = zero4();
        for (int dt = 0; dt < 4; ++dt) o[mi][dt] = zero4();
    }

    const unsigned short* kbase = kq + (size_t)b * S_ * 1024 + h * 128 + 64;
    const unsigned short* vbase = vT + ((size_t)b * NH + h) * HD * S_;
    unsigned short* pw = &Ps[wid][0];

    // staging lane roles (wave-uniform LDS bases; per-lane global addrs)
    int kdh = wid & 1, krh = wid >> 1;           // K: wave -> (d-half, key-half)
    int krow = krh * 16 + (lane >> 2);           // key row 0..31
    int kseg = lane & 3;                         // d segment within half
    int vd = wid * 16 + (lane >> 2);             // V: d row 0..63
    int vseg = lane & 3;                         // key segment

    auto stage = [&](int j0, int buf) {
        gl_lds(kbase + (size_t)(j0 + krow) * 1024 + kdh * 32 + kseg * 8,
               &Ks[buf][kdh * 1024 + krh * 512]);
        gl_lds(vbase + (size_t)vd * S_ + j0 + vseg * 8,
               &Vs[buf][wid * 512]);
    };

    stage(0, 0);

    for (int it = 0; it < S_ / 32; ++it) {
        int cur = it & 1, nxt = cur ^ 1;
        __syncthreads();                          // staging of cur complete
        if (it < S_ / 32 - 1) stage((it + 1) * 32, nxt);

        // K frags from LDS (A-operand now; same lane map as before)
        frag8 kf[2][2];
        for (int kh = 0; kh < 2; ++kh)
            for (int dh = 0; dh < 2; ++dh)
                kf[kh][dh] = *(const frag8*)(&Ks[cur][dh * 1024 + (kh * 16 + l16) * 32 + quad * 8]);

        // S^T = K @ Q^T : lane(quad,l16) holds S^T[key=kh*16+quad*4+r][q=mi*16+l16]
        f32x4 s[2][2];
        for (int mi = 0; mi < 2; ++mi)
            for (int kh = 0; kh < 2; ++kh) {
                f32x4 acc = zero4();
                acc = __builtin_amdgcn_mfma_f32_16x16x32_bf16(kf[kh][0], qf[mi][0], acc, 0, 0, 0);
                acc = __builtin_amdgcn_mfma_f32_16x16x32_bf16(kf[kh][1], qf[mi][1], acc, 0, 0, 0);
                s[mi][kh] = acc;
            }

        // P = exp2(S) -> packed b64 write into P[q][key] (r contiguous)
        for (int mi = 0; mi < 2; ++mi)
            for (int kh = 0; kh < 2; ++kh) {
                float p0 = fexp2(s[mi][kh][0]);
                float p1 = fexp2(s[mi][kh][1]);
                float p2 = fexp2(s[mi][kh][2]);
                float p3 = fexp2(s[mi][kh][3]);
                uint2 pk;
                pk.x = pk2bf(p0, p1);
                pk.y = pk2bf(p2, p3);
                *(uint2*)(&pw[(mi * 16 + l16) * 40 + kh * 16 + quad * 4]) = pk;
            }

        frag8 pf[2];
        pf[0] = *(const frag8*)(&pw[l16 * 40 + quad * 8]);
        pf[1] = *(const frag8*)(&pw[(16 + l16) * 40 + quad * 8]);

        // V frags from LDS: B[n=d][k=key]
        frag8 vf[4];
        for (int dt = 0; dt < 4; ++dt)
            vf[dt] = *(const frag8*)(&Vs[cur][(dt * 16 + l16) * 32 + quad * 8]);

        for (int mi = 0; mi < 2; ++mi) {
            ol[mi] = __builtin_amdgcn_mfma_f32_16x16x32_bf16(pf[mi], ones, ol[mi], 0, 0, 0);
            for (int dt = 0; dt < 4; ++dt)
                o[mi][dt] = __builtin_amdgcn_mfma_f32_16x16x32_bf16(pf[mi], vf[dt], o[mi][dt], 0, 0, 0);
        }
    }

    for (int mi = 0; mi < 2; ++mi)
        for (int r = 0; r < 4; ++r) {
            float inv = 1.0f / ol[mi][r];
            int qrw = q0 + mi * 16 + quad * 4 + r;
            for (int dt = 0; dt < 4; ++dt) {
                int ch = h * HD + dt * 16 + l16;
                attn_out[((size_t)b * S_ + qrw) * C_ + ch] = f2bf(o[mi][dt][r] * inv);
            }
        }
}

// ---------------------------------------------------------------- launch
extern "C" void kernel_launch(void* const* d_in, const int* in_sizes, int n_in,
                              void* d_out, int out_size, void* d_ws, size_t ws_size,
                              hipStream_t stream) {
    const float* x        = (const float*)d_in[0];
    const float* gn_scale = (const float*)d_in[2];
    const float* gn_bias  = (const float*)d_in[3];
    const float* w_qkv    = (const float*)d_in[4];
    const float* b_qkv    = (const float*)d_in[5];
    const float* w_out    = (const float*)d_in[6];
    const float* b_out    = (const float*)d_in[7];
    float* out = (float*)d_out;

    char* ws = (char*)d_ws;
    unsigned short* xn    = (unsigned short*)(ws);                          // 8 MB
    unsigned short* kq    = (unsigned short*)(ws + ((size_t)8  << 20));     // 16 MB
    unsigned short* attn  = (unsigned short*)(ws + ((size_t)24 << 20));     // 8 MB
    unsigned short* vT    = (unsigned short*)(ws + ((size_t)32 << 20));     // 8 MB
    unsigned short* wqkvT = (unsigned short*)(ws + ((size_t)40 << 20));     // 1.5 MB
    unsigned short* woutT = (unsigned short*)(ws + ((size_t)40 << 20) + ((size_t)3 << 19)); // 0.5 MB

    transpose_kernel<<<dim3(QKVC / 32, C_ / 32), 256, 0, stream>>>(w_qkv, wqkvT, C_, QKVC);
    transpose_kernel<<<dim3(C_ / 32, C_ / 32), 256, 0, stream>>>(w_out, woutT, C_, C_);

    gn_kernel<<<dim3(B_ * GROUPS), 256, 0, stream>>>(x, gn_scale, gn_bias, xn);

    gemm_kernel<0><<<dim3(QKVC / 128, (B_ * S_) / 128), 256, 0, stream>>>(
        xn, wqkvT, b_qkv, nullptr, kq, vT, nullptr, B_ * S_, QKVC, C_);

    attn_kernel<<<dim3(512), 256, 0, stream>>>(kq, vT, attn);

    gemm_kernel<1><<<dim3(C_ / 128, (B_ * S_) / 128), 256, 0, stream>>>(
        attn, woutT, b_out, xn, nullptr, nullptr, out, B_ * S_, C_, C_);
}

// Round 10
// 164.792 us; speedup vs baseline: 2.0526x; 1.0361x over previous
//
#include <hip/hip_runtime.h>
#include <hip/hip_bf16.h>

// AttentionBlock: GroupNorm -> QKV -> MHA (8 heads, hd=64, s=1024) -> out proj -> +xn
// Inputs/outputs FP32; internally bf16 for MFMA.
//
// r10: attn was grid-limited (512 blocks = 2 blocks/CU = 25% occupancy cap).
// Split q-tiles to 64 rows/block -> 1024 blocks = 4 blocks/CU = 50% occ,
// 16 q-rows/wave, same r9 inner body (S^T trick, packed P b64 writes, exp2).
// Transposes merged into one launch.
//
// ws: xn 8MB @0 | kq 16MB @8 | attn 8MB @24 | vT 8MB @32 | wqkvT 1.5MB @40 | woutT .5MB @41.5

#define B_    8
#define S_    1024
#define C_    512
#define NH    8
#define HD    64
#define QKVC  1536
#define GROUPS 32
#define GSIZE  16
#define EPSV   1e-5f
#define QSCL  0.18033688f   // 0.125 * log2(e)

using frag8 = __attribute__((ext_vector_type(8))) short;   // 8 bf16 = 4 VGPR
using f32x4 = __attribute__((ext_vector_type(4))) float;

__device__ __forceinline__ float bf2f(unsigned short u) {
    union { unsigned int i; float f; } v; v.i = ((unsigned int)u) << 16; return v.f;
}
__device__ __forceinline__ unsigned short f2bf(float f) {
    union { float f; unsigned int i; } v; v.f = f;
    unsigned int x = v.i;
    return (unsigned short)((x + 0x7fffu + ((x >> 16) & 1u)) >> 16);
}
// pack two fp32 -> two bf16 (round-half-up) in one dword: 2 adds + 1 v_perm
__device__ __forceinline__ unsigned int pk2bf(float a, float b) {
    union { float f; unsigned int u; } x, y; x.f = a; y.f = b;
    return __builtin_amdgcn_perm(y.u + 0x8000u, x.u + 0x8000u, 0x07060302u);
}
__device__ __forceinline__ float fexp2(float x) {
#if __has_builtin(__builtin_amdgcn_exp2f)
    return __builtin_amdgcn_exp2f(x);
#else
    return exp2f(x);
#endif
}
__device__ __forceinline__ f32x4 zero4() {
    f32x4 z; z[0] = 0.f; z[1] = 0.f; z[2] = 0.f; z[3] = 0.f; return z;
}
__device__ __forceinline__ void gl_lds(const unsigned short* gp, unsigned short* lp) {
    __builtin_amdgcn_global_load_lds(
        (const __attribute__((address_space(1))) void*)gp,
        (__attribute__((address_space(3))) void*)lp, 16, 0, 0);
}

// ---------------------------------------------------------------- transpose
// merged: blocks 0..767 -> w_qkv [512][1536]->wqkvT; 768..1023 -> w_out
__global__ __launch_bounds__(256) void transpose2_kernel(
        const float* __restrict__ w_qkv, const float* __restrict__ w_out,
        unsigned short* __restrict__ wqkvT, unsigned short* __restrict__ woutT) {
    __shared__ float tile[32][33];
    int id = blockIdx.x;
    const float* in; unsigned short* out; int N, n0, k0;
    if (id < 768) { in = w_qkv; out = wqkvT; N = QKVC; n0 = (id % 48) * 32; k0 = (id / 48) * 32; }
    else { id -= 768; in = w_out; out = woutT; N = C_; n0 = (id % 16) * 32; k0 = (id / 16) * 32; }
    int t = threadIdx.x;
    for (int i = 0; i < 4; ++i) {
        int idx = t + i * 256; int r = idx >> 5, c = idx & 31;
        tile[r][c] = in[(size_t)(k0 + r) * N + n0 + c];
    }
    __syncthreads();
    for (int i = 0; i < 4; ++i) {
        int idx = t + i * 256; int r = idx >> 5, c = idx & 31;
        out[(size_t)(n0 + r) * C_ + k0 + c] = f2bf(tile[c][r]);
    }
}

// ---------------------------------------------------------------- groupnorm
// (r4 version — proven passing)
__global__ __launch_bounds__(256) void gn_kernel(
        const float* __restrict__ x,
        const float* __restrict__ scale,
        const float* __restrict__ bias,
        unsigned short* __restrict__ xn) {
    int bg = blockIdx.x;
    int b = bg >> 5, g = bg & 31;
    const float* xb = x + (size_t)b * S_ * C_;
    int t = threadIdx.x;

    float sum = 0.f, ss = 0.f;
    for (int i = 0; i < 16; ++i) {
        int idx = t + i * 256;
        int row = idx >> 2, j = idx & 3;
        float4 v = *(const float4*)(xb + (size_t)row * C_ + g * GSIZE + j * 4);
        sum += v.x + v.y + v.z + v.w;
        ss  += v.x * v.x + v.y * v.y + v.z * v.z + v.w * v.w;
    }
    for (int off = 1; off < 64; off <<= 1) {
        sum += __shfl_xor(sum, off);
        ss  += __shfl_xor(ss,  off);
    }
    __shared__ float s_sum[4], s_ss[4];
    int wid = t >> 6;
    if ((t & 63) == 0) { s_sum[wid] = sum; s_ss[wid] = ss; }
    __syncthreads();
    sum = s_sum[0] + s_sum[1] + s_sum[2] + s_sum[3];
    ss  = s_ss[0]  + s_ss[1]  + s_ss[2]  + s_ss[3];
    float mean = sum * (1.f / 16384.f);
    float var  = ss * (1.f / 16384.f) - mean * mean;
    float rinv = rsqrtf(var + EPSV);

    float sc[16], bi[16];
    for (int u = 0; u < 16; ++u) {
        sc[u] = scale[g * GSIZE + u];
        bi[u] = bias[g * GSIZE + u];
    }
    for (int i = 0; i < 16; ++i) {
        int idx = t + i * 256;
        int row = idx >> 2, j = idx & 3;
        float4 v = *(const float4*)(xb + (size_t)row * C_ + g * GSIZE + j * 4);
        int c0 = j * 4;
        float f0 = (v.x - mean) * rinv * sc[c0 + 0] + bi[c0 + 0];
        float f1 = (v.y - mean) * rinv * sc[c0 + 1] + bi[c0 + 1];
        float f2 = (v.z - mean) * rinv * sc[c0 + 2] + bi[c0 + 2];
        float f3 = (v.w - mean) * rinv * sc[c0 + 3] + bi[c0 + 3];
        uint2 o;
        o.x = (unsigned int)f2bf(f0) | ((unsigned int)f2bf(f1) << 16);
        o.y = (unsigned int)f2bf(f2) | ((unsigned int)f2bf(f3) << 16);
        *(uint2*)(xn + (size_t)b * S_ * C_ + (size_t)row * C_ + g * GSIZE + c0) = o;
    }
}

// ---------------------------------------------------------------- GEMM
// (r9 version — 128x128 tile, BK=32, A+B via global_load_lds, double-buffered)
template<int MODE>
__global__ __launch_bounds__(256) void gemm_kernel(
        const unsigned short* __restrict__ A,
        const unsigned short* __restrict__ Bt,
        const float* __restrict__ bias,
        const unsigned short* __restrict__ resid,
        unsigned short* __restrict__ outA,   // MODE0: kq [M][1024]
        unsigned short* __restrict__ outV,   // MODE0: vT [b][h][64][1024]
        float* __restrict__ outF,            // MODE1: fp32 [M][N]
        int M, int N, int K) {
    __shared__ unsigned short As[2][128 * 32];
    __shared__ unsigned short Bs[2][128 * 32];
    int m0 = blockIdx.y * 128, n0 = blockIdx.x * 128;
    int t = threadIdx.x;
    int wid = t >> 6, lane = t & 63;
    int quad = lane >> 4, l16 = lane & 15;
    int wm = (wid >> 1) * 64, wn = (wid & 1) * 64;

    f32x4 acc[4][4];
    for (int mi = 0; mi < 4; ++mi)
        for (int ni = 0; ni < 4; ++ni) acc[mi][ni] = zero4();

    int srow = t >> 2, sseg = t & 3;             // staging roles
    auto stage = [&](int k0, int buf) {
        for (int i = 0; i < 2; ++i) {
            gl_lds(A + (size_t)(m0 + i * 64 + srow) * K + k0 + sseg * 8,
                   &As[buf][(size_t)(i * 256 + wid * 64) * 8]);
            gl_lds(Bt + (size_t)(n0 + i * 64 + srow) * K + k0 + sseg * 8,
                   &Bs[buf][(size_t)(i * 256 + wid * 64) * 8]);
        }
    };

    stage(0, 0);
    int nk = K >> 5;
    for (int i = 0; i < nk; ++i) {
        __syncthreads();
        if (i + 1 < nk) stage((i + 1) << 5, (i + 1) & 1);
        int buf = i & 1;

        frag8 bfrag[4], afrag[4];
        for (int ni = 0; ni < 4; ++ni)
            bfrag[ni] = *(const frag8*)(&Bs[buf][(wn + ni * 16 + l16) * 32 + quad * 8]);
        for (int mi = 0; mi < 4; ++mi)
            afrag[mi] = *(const frag8*)(&As[buf][(wm + mi * 16 + l16) * 32 + quad * 8]);

        for (int mi = 0; mi < 4; ++mi)
            for (int ni = 0; ni < 4; ++ni)
                acc[mi][ni] = __builtin_amdgcn_mfma_f32_16x16x32_bf16(
                    afrag[mi], bfrag[ni], acc[mi][ni], 0, 0, 0);
    }

    for (int ni = 0; ni < 4; ++ni) {
        int c0 = n0 + wn + ni * 16;
        float bv = bias[c0 + l16];
        if (MODE == 0) {
            int h = c0 / 192, rr = c0 % 192;
            if (rr >= 128) {
                int d = rr - 128 + l16;
                int bidx = m0 >> 10;
                unsigned short* vp = outV + (((size_t)bidx * NH + h) * HD + d) * S_
                                   + (m0 & 1023) + wm + quad * 4;
                for (int mi = 0; mi < 4; ++mi) {
                    uint2 pk;
                    pk.x = pk2bf(acc[mi][ni][0] + bv, acc[mi][ni][1] + bv);
                    pk.y = pk2bf(acc[mi][ni][2] + bv, acc[mi][ni][3] + bv);
                    *(uint2*)(vp + mi * 16) = pk;
                }
            } else {
                float scl = (rr < 64) ? QSCL : 1.0f;   // q pre-scaled by log2e/8
                int colk = h * 128 + rr + l16;
                for (int mi = 0; mi < 4; ++mi)
                    for (int r = 0; r < 4; ++r) {
                        int row = m0 + wm + mi * 16 + quad * 4 + r;
                        outA[(size_t)row * 1024 + colk] = f2bf((acc[mi][ni][r] + bv) * scl);
                    }
            }
        } else {
            int col = c0 + l16;
            for (int mi = 0; mi < 4; ++mi)
                for (int r = 0; r < 4; ++r) {
                    int row = m0 + wm + mi * 16 + quad * 4 + r;
                    float v = acc[mi][ni][r] + bv + bf2f(resid[(size_t)row * N + col]);
                    outF[(size_t)row * N + col] = v;
                }
        }
    }
}

// ---------------------------------------------------------------- attention
// 1024 blocks (XCD-swizzled: 16 q-tiles of each (b,h) share an XCD),
// 4 waves x 16 q-rows (4 blocks/CU = 50% occ), 32 keys/iter.
// K/V LDS-staged (double-buffered, 1 barrier/iter). S^T = K@Q^T; P = v_exp;
// packed b64 P-writes; l via ones-MFMA.
__global__ __launch_bounds__(256) void attn_kernel(
        const unsigned short* __restrict__ kq,   // [b*s][h*128 + (q|k)]
        const unsigned short* __restrict__ vT,   // [b][h][d][s]
        unsigned short* __restrict__ attn_out) { // [b][s][512]
    int i = blockIdx.x;
    int xcd = i & 7, slot = i >> 3;              // slot 0..127
    int bh = xcd * 8 + (slot >> 4);              // 8 (b,h) pairs per XCD
    int qt = slot & 15;
    int b = bh >> 3, h = bh & 7;

    int t = threadIdx.x;
    int wid = t >> 6, lane = t & 63, quad = lane >> 4, l16 = lane & 15;
    int q0 = qt * 64 + wid * 16;

    __shared__ unsigned short Ks[2][2048];       // K tile [dh][key32][d32]
    __shared__ unsigned short Vs[2][2048];       // V tile [d64][key32]
    __shared__ unsigned short Ps[4][16 * 40];    // wave-private P[q16][key32]

    // Q B-fragments: B[n=q][k=d] (one-time scattered load, prologue only)
    const unsigned short* qrow = kq + ((size_t)b * S_ + q0 + l16) * 1024 + h * 128;
    frag8 qf0 = *(const frag8*)(qrow + quad * 8);
    frag8 qf1 = *(const frag8*)(qrow + 32 + quad * 8);

    frag8 ones;
    for (int i2 = 0; i2 < 8; ++i2) ones[i2] = (short)0x3f80;   // bf16 1.0

    f32x4 o[4], ol;
    ol = zero4();
    for (int dt = 0; dt < 4; ++dt) o[dt] = zero4();

    const unsigned short* kbase = kq + (size_t)b * S_ * 1024 + h * 128 + 64;
    const unsigned short* vbase = vT + ((size_t)b * NH + h) * HD * S_;
    unsigned short* pw = &Ps[wid][0];

    // staging lane roles (wave-uniform LDS bases; per-lane global addrs)
    int kdh = wid & 1, krh = wid >> 1;           // K: wave -> (d-half, key-half)
    int krow = krh * 16 + (lane >> 2);           // key row 0..31
    int kseg = lane & 3;                         // d segment within half
    int vd = wid * 16 + (lane >> 2);             // V: d row 0..63
    int vseg = lane & 3;                         // key segment

    auto stage = [&](int j0, int buf) {
        gl_lds(kbase + (size_t)(j0 + krow) * 1024 + kdh * 32 + kseg * 8,
               &Ks[buf][kdh * 1024 + krh * 512]);
        gl_lds(vbase + (size_t)vd * S_ + j0 + vseg * 8,
               &Vs[buf][wid * 512]);
    };

    stage(0, 0);

    for (int it = 0; it < S_ / 32; ++it) {
        int cur = it & 1, nxt = cur ^ 1;
        __syncthreads();                          // staging of cur complete
        if (it < S_ / 32 - 1) stage((it + 1) * 32, nxt);

        // K frags from LDS (A-operand): A[m=key=kh*16+l16][k=d]
        frag8 kf[2][2];
        for (int kh = 0; kh < 2; ++kh)
            for (int dh = 0; dh < 2; ++dh)
                kf[kh][dh] = *(const frag8*)(&Ks[cur][dh * 1024 + (kh * 16 + l16) * 32 + quad * 8]);

        // S^T = K @ Q^T : lane holds S^T[key=kh*16+quad*4+r][q=l16]
        f32x4 s[2];
        for (int kh = 0; kh < 2; ++kh) {
            f32x4 acc = zero4();
            acc = __builtin_amdgcn_mfma_f32_16x16x32_bf16(kf[kh][0], qf0, acc, 0, 0, 0);
            acc = __builtin_amdgcn_mfma_f32_16x16x32_bf16(kf[kh][1], qf1, acc, 0, 0, 0);
            s[kh] = acc;
        }

        // P = exp2(S) -> packed b64 write into P[q][key] (r contiguous)
        for (int kh = 0; kh < 2; ++kh) {
            float p0 = fexp2(s[kh][0]);
            float p1 = fexp2(s[kh][1]);
            float p2 = fexp2(s[kh][2]);
            float p3 = fexp2(s[kh][3]);
            uint2 pk;
            pk.x = pk2bf(p0, p1);
            pk.y = pk2bf(p2, p3);
            *(uint2*)(&pw[l16 * 40 + kh * 16 + quad * 4]) = pk;
        }

        frag8 pf = *(const frag8*)(&pw[l16 * 40 + quad * 8]);

        // V frags from LDS: B[n=d][k=key]
        frag8 vf[4];
        for (int dt = 0; dt < 4; ++dt)
            vf[dt] = *(const frag8*)(&Vs[cur][(dt * 16 + l16) * 32 + quad * 8]);

        ol = __builtin_amdgcn_mfma_f32_16x16x32_bf16(pf, ones, ol, 0, 0, 0);
        for (int dt = 0; dt < 4; ++dt)
            o[dt] = __builtin_amdgcn_mfma_f32_16x16x32_bf16(pf, vf[dt], o[dt], 0, 0, 0);
    }

    // O C-layout: lane(quad,l16) holds O[q=quad*4+r][d=dt*16+l16]; ol same rows
    for (int r = 0; r < 4; ++r) {
        float inv = 1.0f / ol[r];
        int qrw = q0 + quad * 4 + r;
        for (int dt = 0; dt < 4; ++dt) {
            int ch = h * HD + dt * 16 + l16;
            attn_out[((size_t)b * S_ + qrw) * C_ + ch] = f2bf(o[dt][r] * inv);
        }
    }
}

// ---------------------------------------------------------------- launch
extern "C" void kernel_launch(void* const* d_in, const int* in_sizes, int n_in,
                              void* d_out, int out_size, void* d_ws, size_t ws_size,
                              hipStream_t stream) {
    const float* x        = (const float*)d_in[0];
    const float* gn_scale = (const float*)d_in[2];
    const float* gn_bias  = (const float*)d_in[3];
    const float* w_qkv    = (const float*)d_in[4];
    const float* b_qkv    = (const float*)d_in[5];
    const float* w_out    = (const float*)d_in[6];
    const float* b_out    = (const float*)d_in[7];
    float* out = (float*)d_out;

    char* ws = (char*)d_ws;
    unsigned short* xn    = (unsigned short*)(ws);                          // 8 MB
    unsigned short* kq    = (unsigned short*)(ws + ((size_t)8  << 20));     // 16 MB
    unsigned short* attn  = (unsigned short*)(ws + ((size_t)24 << 20));     // 8 MB
    unsigned short* vT    = (unsigned short*)(ws + ((size_t)32 << 20));     // 8 MB
    unsigned short* wqkvT = (unsigned short*)(ws + ((size_t)40 << 20));     // 1.5 MB
    unsigned short* woutT = (unsigned short*)(ws + ((size_t)40 << 20) + ((size_t)3 << 19)); // 0.5 MB

    transpose2_kernel<<<dim3(1024), 256, 0, stream>>>(w_qkv, w_out, wqkvT, woutT);

    gn_kernel<<<dim3(B_ * GROUPS), 256, 0, stream>>>(x, gn_scale, gn_bias, xn);

    gemm_kernel<0><<<dim3(QKVC / 128, (B_ * S_) / 128), 256, 0, stream>>>(
        xn, wqkvT, b_qkv, nullptr, kq, vT, nullptr, B_ * S_, QKVC, C_);

    attn_kernel<<<dim3(1024), 256, 0, stream>>>(kq, vT, attn);

    gemm_kernel<1><<<dim3(C_ / 128, (B_ * S_) / 128), 256, 0, stream>>>(
        attn, woutT, b_out, xn, nullptr, nullptr, out, B_ * S_, C_, C_);
}

// Round 11
// 160.187 us; speedup vs baseline: 2.1116x; 1.0288x over previous
//
#include <hip/hip_runtime.h>
#include <hip/hip_bf16.h>

// AttentionBlock: GroupNorm -> QKV -> MHA (8 heads, hd=64, s=1024) -> out proj -> +xn
// Inputs/outputs FP32; internally bf16 for MFMA.
//
// r11: P never touches LDS. S^T C-layout gives lane(quad,l16) the 8 P-values
// {keys quad*4+r | kh=0,1} for q=l16; PV A-frag wants k-pos 8*quad+j. MFMA
// contraction is order-invariant -> relabel positions sigma(kh,quad,r) =
// 8*quad+4*kh+r, build P frag in registers, stage V with the same key
// permutation (two aligned ds_write_b64 from one 16B load per lane).
// Also: gn fused into the prep (transpose) kernel -> 4 launches total.
//
// ws: xn 8MB @0 | kq 16MB @8 | attn 8MB @24 | vT 8MB @32 | wqkvT 1.5MB @40 | woutT .5MB @41.5

#define B_    8
#define S_    1024
#define C_    512
#define NH    8
#define HD    64
#define QKVC  1536
#define GROUPS 32
#define GSIZE  16
#define EPSV   1e-5f
#define QSCL  0.18033688f   // 0.125 * log2(e)

using frag8 = __attribute__((ext_vector_type(8))) short;   // 8 bf16 = 4 VGPR
using f32x4 = __attribute__((ext_vector_type(4))) float;

__device__ __forceinline__ float bf2f(unsigned short u) {
    union { unsigned int i; float f; } v; v.i = ((unsigned int)u) << 16; return v.f;
}
__device__ __forceinline__ unsigned short f2bf(float f) {
    union { float f; unsigned int i; } v; v.f = f;
    unsigned int x = v.i;
    return (unsigned short)((x + 0x7fffu + ((x >> 16) & 1u)) >> 16);
}
// pack two fp32 -> two bf16 (round-half-up) in one dword: low=a, high=b
__device__ __forceinline__ unsigned int pk2bf(float a, float b) {
    union { float f; unsigned int u; } x, y; x.f = a; y.f = b;
    return __builtin_amdgcn_perm(y.u + 0x8000u, x.u + 0x8000u, 0x07060302u);
}
__device__ __forceinline__ float fexp2(float x) {
#if __has_builtin(__builtin_amdgcn_exp2f)
    return __builtin_amdgcn_exp2f(x);
#else
    return exp2f(x);
#endif
}
__device__ __forceinline__ f32x4 zero4() {
    f32x4 z; z[0] = 0.f; z[1] = 0.f; z[2] = 0.f; z[3] = 0.f; return z;
}
__device__ __forceinline__ void gl_lds(const unsigned short* gp, unsigned short* lp) {
    __builtin_amdgcn_global_load_lds(
        (const __attribute__((address_space(1))) void*)gp,
        (__attribute__((address_space(3))) void*)lp, 16, 0, 0);
}

// ---------------------------------------------------------------- prep
// blocks 0..767: transpose w_qkv; 768..1023: transpose w_out; 1024..1279: gn
__global__ __launch_bounds__(256) void prep_kernel(
        const float* __restrict__ w_qkv, const float* __restrict__ w_out,
        unsigned short* __restrict__ wqkvT, unsigned short* __restrict__ woutT,
        const float* __restrict__ x,
        const float* __restrict__ scale, const float* __restrict__ bias,
        unsigned short* __restrict__ xn) {
    __shared__ float tile[32][33];
    int id = blockIdx.x;
    int t = threadIdx.x;
    if (id < 1024) {
        const float* in; unsigned short* out; int N, n0, k0;
        if (id < 768) { in = w_qkv; out = wqkvT; N = QKVC; n0 = (id % 48) * 32; k0 = (id / 48) * 32; }
        else { int i2 = id - 768; in = w_out; out = woutT; N = C_; n0 = (i2 % 16) * 32; k0 = (i2 / 16) * 32; }
        for (int i = 0; i < 4; ++i) {
            int idx = t + i * 256; int r = idx >> 5, c = idx & 31;
            tile[r][c] = in[(size_t)(k0 + r) * N + n0 + c];
        }
        __syncthreads();
        for (int i = 0; i < 4; ++i) {
            int idx = t + i * 256; int r = idx >> 5, c = idx & 31;
            out[(size_t)(n0 + r) * C_ + k0 + c] = f2bf(tile[c][r]);
        }
        return;
    }
    // ---- groupnorm (r4 body, proven)
    int bg = id - 1024;
    int b = bg >> 5, g = bg & 31;
    const float* xb = x + (size_t)b * S_ * C_;

    float sum = 0.f, ss = 0.f;
    for (int i = 0; i < 16; ++i) {
        int idx = t + i * 256;
        int row = idx >> 2, j = idx & 3;
        float4 v = *(const float4*)(xb + (size_t)row * C_ + g * GSIZE + j * 4);
        sum += v.x + v.y + v.z + v.w;
        ss  += v.x * v.x + v.y * v.y + v.z * v.z + v.w * v.w;
    }
    for (int off = 1; off < 64; off <<= 1) {
        sum += __shfl_xor(sum, off);
        ss  += __shfl_xor(ss,  off);
    }
    __shared__ float s_sum[4], s_ss[4];
    int wid = t >> 6;
    if ((t & 63) == 0) { s_sum[wid] = sum; s_ss[wid] = ss; }
    __syncthreads();
    sum = s_sum[0] + s_sum[1] + s_sum[2] + s_sum[3];
    ss  = s_ss[0]  + s_ss[1]  + s_ss[2]  + s_ss[3];
    float mean = sum * (1.f / 16384.f);
    float var  = ss * (1.f / 16384.f) - mean * mean;
    float rinv = rsqrtf(var + EPSV);

    float sc[16], bi[16];
    for (int u = 0; u < 16; ++u) {
        sc[u] = scale[g * GSIZE + u];
        bi[u] = bias[g * GSIZE + u];
    }
    for (int i = 0; i < 16; ++i) {
        int idx = t + i * 256;
        int row = idx >> 2, j = idx & 3;
        float4 v = *(const float4*)(xb + (size_t)row * C_ + g * GSIZE + j * 4);
        int c0 = j * 4;
        float f0 = (v.x - mean) * rinv * sc[c0 + 0] + bi[c0 + 0];
        float f1 = (v.y - mean) * rinv * sc[c0 + 1] + bi[c0 + 1];
        float f2 = (v.z - mean) * rinv * sc[c0 + 2] + bi[c0 + 2];
        float f3 = (v.w - mean) * rinv * sc[c0 + 3] + bi[c0 + 3];
        uint2 o;
        o.x = (unsigned int)f2bf(f0) | ((unsigned int)f2bf(f1) << 16);
        o.y = (unsigned int)f2bf(f2) | ((unsigned int)f2bf(f3) << 16);
        *(uint2*)(xn + (size_t)b * S_ * C_ + (size_t)row * C_ + g * GSIZE + c0) = o;
    }
}

// ---------------------------------------------------------------- GEMM
// (r9 version — 128x128 tile, BK=32, A+B via global_load_lds, double-buffered)
template<int MODE>
__global__ __launch_bounds__(256) void gemm_kernel(
        const unsigned short* __restrict__ A,
        const unsigned short* __restrict__ Bt,
        const float* __restrict__ bias,
        const unsigned short* __restrict__ resid,
        unsigned short* __restrict__ outA,   // MODE0: kq [M][1024]
        unsigned short* __restrict__ outV,   // MODE0: vT [b][h][64][1024]
        float* __restrict__ outF,            // MODE1: fp32 [M][N]
        int M, int N, int K) {
    __shared__ unsigned short As[2][128 * 32];
    __shared__ unsigned short Bs[2][128 * 32];
    int m0 = blockIdx.y * 128, n0 = blockIdx.x * 128;
    int t = threadIdx.x;
    int wid = t >> 6, lane = t & 63;
    int quad = lane >> 4, l16 = lane & 15;
    int wm = (wid >> 1) * 64, wn = (wid & 1) * 64;

    f32x4 acc[4][4];
    for (int mi = 0; mi < 4; ++mi)
        for (int ni = 0; ni < 4; ++ni) acc[mi][ni] = zero4();

    int srow = t >> 2, sseg = t & 3;             // staging roles
    auto stage = [&](int k0, int buf) {
        for (int i = 0; i < 2; ++i) {
            gl_lds(A + (size_t)(m0 + i * 64 + srow) * K + k0 + sseg * 8,
                   &As[buf][(size_t)(i * 256 + wid * 64) * 8]);
            gl_lds(Bt + (size_t)(n0 + i * 64 + srow) * K + k0 + sseg * 8,
                   &Bs[buf][(size_t)(i * 256 + wid * 64) * 8]);
        }
    };

    stage(0, 0);
    int nk = K >> 5;
    for (int i = 0; i < nk; ++i) {
        __syncthreads();
        if (i + 1 < nk) stage((i + 1) << 5, (i + 1) & 1);
        int buf = i & 1;

        frag8 bfrag[4], afrag[4];
        for (int ni = 0; ni < 4; ++ni)
            bfrag[ni] = *(const frag8*)(&Bs[buf][(wn + ni * 16 + l16) * 32 + quad * 8]);
        for (int mi = 0; mi < 4; ++mi)
            afrag[mi] = *(const frag8*)(&As[buf][(wm + mi * 16 + l16) * 32 + quad * 8]);

        for (int mi = 0; mi < 4; ++mi)
            for (int ni = 0; ni < 4; ++ni)
                acc[mi][ni] = __builtin_amdgcn_mfma_f32_16x16x32_bf16(
                    afrag[mi], bfrag[ni], acc[mi][ni], 0, 0, 0);
    }

    for (int ni = 0; ni < 4; ++ni) {
        int c0 = n0 + wn + ni * 16;
        float bv = bias[c0 + l16];
        if (MODE == 0) {
            int h = c0 / 192, rr = c0 % 192;
            if (rr >= 128) {
                int d = rr - 128 + l16;
                int bidx = m0 >> 10;
                unsigned short* vp = outV + (((size_t)bidx * NH + h) * HD + d) * S_
                                   + (m0 & 1023) + wm + quad * 4;
                for (int mi = 0; mi < 4; ++mi) {
                    uint2 pk;
                    pk.x = pk2bf(acc[mi][ni][0] + bv, acc[mi][ni][1] + bv);
                    pk.y = pk2bf(acc[mi][ni][2] + bv, acc[mi][ni][3] + bv);
                    *(uint2*)(vp + mi * 16) = pk;
                }
            } else {
                float scl = (rr < 64) ? QSCL : 1.0f;   // q pre-scaled by log2e/8
                int colk = h * 128 + rr + l16;
                for (int mi = 0; mi < 4; ++mi)
                    for (int r = 0; r < 4; ++r) {
                        int row = m0 + wm + mi * 16 + quad * 4 + r;
                        outA[(size_t)row * 1024 + colk] = f2bf((acc[mi][ni][r] + bv) * scl);
                    }
            }
        } else {
            int col = c0 + l16;
            for (int mi = 0; mi < 4; ++mi)
                for (int r = 0; r < 4; ++r) {
                    int row = m0 + wm + mi * 16 + quad * 4 + r;
                    float v = acc[mi][ni][r] + bv + bf2f(resid[(size_t)row * N + col]);
                    outF[(size_t)row * N + col] = v;
                }
        }
    }
}

// ---------------------------------------------------------------- attention
// 1024 blocks (XCD-swizzled), 4 waves x 16 q-rows, 32 keys/iter.
// S^T = K@Q^T; P built IN REGISTERS as the PV A-frag under key relabeling
// sigma(kh,quad,r) = 8*quad + 4*kh + r; V staged with the same permutation:
//   position p: quad=p>>3, kh=(p>>2)&1, r=p&3 -> true key = 16*kh+4*quad+r.
//   Staging lane (d=vd, seg): loads true keys 8*seg+u (u=0..7, one uint4);
//   kh=seg>>1, s'=seg&1: u=0..3 -> pos 16*s'+4*kh+u; u=4..7 -> +8.
// l via ones-MFMA. K staged via gl_lds as before. No Ps buffer.
__global__ __launch_bounds__(256) void attn_kernel(
        const unsigned short* __restrict__ kq,   // [b*s][h*128 + (q|k)]
        const unsigned short* __restrict__ vT,   // [b][h][d][s]
        unsigned short* __restrict__ attn_out) { // [b][s][512]
    int i = blockIdx.x;
    int xcd = i & 7, slot = i >> 3;              // slot 0..127
    int bh = xcd * 8 + (slot >> 4);              // 8 (b,h) pairs per XCD
    int qt = slot & 15;
    int b = bh >> 3, h = bh & 7;

    int t = threadIdx.x;
    int wid = t >> 6, lane = t & 63, quad = lane >> 4, l16 = lane & 15;
    int q0 = qt * 64 + wid * 16;

    __shared__ unsigned short Ks[2][2048];       // K tile [dh][key32][d32]
    __shared__ unsigned short Vs[2][2048];       // V tile [d64][pos32] (permuted)

    // Q B-fragments: B[n=q][k=d] (one-time scattered load, prologue only)
    const unsigned short* qrow = kq + ((size_t)b * S_ + q0 + l16) * 1024 + h * 128;
    frag8 qf0 = *(const frag8*)(qrow + quad * 8);
    frag8 qf1 = *(const frag8*)(qrow + 32 + quad * 8);

    frag8 ones;
    for (int i2 = 0; i2 < 8; ++i2) ones[i2] = (short)0x3f80;   // bf16 1.0

    f32x4 o[4], ol;
    ol = zero4();
    for (int dt = 0; dt < 4; ++dt) o[dt] = zero4();

    const unsigned short* kbase = kq + (size_t)b * S_ * 1024 + h * 128 + 64;
    const unsigned short* vbase = vT + ((size_t)b * NH + h) * HD * S_;

    // K staging roles (gl_lds, wave-uniform LDS base)
    int kdh = wid & 1, krh = wid >> 1;
    int krow = krh * 16 + (lane >> 2);
    int kseg = lane & 3;
    // V staging roles (explicit load + permuted b64 writes)
    int vd = wid * 16 + (lane >> 2);             // d row 0..63
    int vseg = lane & 3;                         // true-key segment (8 keys)
    int vkh = vseg >> 1, vsp = vseg & 1;
    int vbase1 = vsp * 16 + vkh * 4;             // pos of u=0..3; +8 for u=4..7

    auto stageK = [&](int j0, int buf) {
        gl_lds(kbase + (size_t)(j0 + krow) * 1024 + kdh * 32 + kseg * 8,
               &Ks[buf][kdh * 1024 + krh * 512]);
    };
    auto loadV = [&](int j0) {
        return *(const uint4*)(vbase + (size_t)vd * S_ + j0 + vseg * 8);
    };
    auto writeV = [&](uint4 w, int buf) {
        unsigned short* vdst = &Vs[buf][vd * 32];
        uint2 g1; g1.x = w.x; g1.y = w.y;
        uint2 g2; g2.x = w.z; g2.y = w.w;
        *(uint2*)(vdst + vbase1)     = g1;       // positions vbase1..+3
        *(uint2*)(vdst + vbase1 + 8) = g2;       // positions vbase1+8..+11
    };

    stageK(0, 0);
    writeV(loadV(0), 0);

    for (int it = 0; it < S_ / 32; ++it) {
        int cur = it & 1, nxt = cur ^ 1;
        __syncthreads();                          // staging of cur visible
        uint4 vnext;
        bool more = (it < S_ / 32 - 1);
        if (more) {
            stageK((it + 1) * 32, nxt);
            vnext = loadV((it + 1) * 32);         // consumed at end of iter
        }

        // K frags from LDS (A-operand): A[m=key=kh*16+l16][k=d]
        frag8 kf[2][2];
        for (int kh = 0; kh < 2; ++kh)
            for (int dh = 0; dh < 2; ++dh)
                kf[kh][dh] = *(const frag8*)(&Ks[cur][dh * 1024 + (kh * 16 + l16) * 32 + quad * 8]);

        // S^T = K @ Q^T : lane holds S^T[key=kh*16+quad*4+r][q=l16]
        f32x4 s[2];
        for (int kh = 0; kh < 2; ++kh) {
            f32x4 acc = zero4();
            acc = __builtin_amdgcn_mfma_f32_16x16x32_bf16(kf[kh][0], qf0, acc, 0, 0, 0);
            acc = __builtin_amdgcn_mfma_f32_16x16x32_bf16(kf[kh][1], qf1, acc, 0, 0, 0);
            s[kh] = acc;
        }

        // P A-frag built in registers: element j<4 -> (kh=0,r=j); j>=4 -> (kh=1,r=j-4)
        union { frag8 f; unsigned int u[4]; } pfu;
        pfu.u[0] = pk2bf(fexp2(s[0][0]), fexp2(s[0][1]));
        pfu.u[1] = pk2bf(fexp2(s[0][2]), fexp2(s[0][3]));
        pfu.u[2] = pk2bf(fexp2(s[1][0]), fexp2(s[1][1]));
        pfu.u[3] = pk2bf(fexp2(s[1][2]), fexp2(s[1][3]));

        // V frags from LDS (permuted positions): B[n=d][k=pos=quad*8+j]
        frag8 vf[4];
        for (int dt = 0; dt < 4; ++dt)
            vf[dt] = *(const frag8*)(&Vs[cur][(dt * 16 + l16) * 32 + quad * 8]);

        ol = __builtin_amdgcn_mfma_f32_16x16x32_bf16(pfu.f, ones, ol, 0, 0, 0);
        for (int dt = 0; dt < 4; ++dt)
            o[dt] = __builtin_amdgcn_mfma_f32_16x16x32_bf16(pfu.f, vf[dt], o[dt], 0, 0, 0);

        if (more) writeV(vnext, nxt);             // visible after next barrier
    }

    // O C-layout: lane(quad,l16) holds O[q=quad*4+r][d=dt*16+l16]; ol same rows
    for (int r = 0; r < 4; ++r) {
        float inv = 1.0f / ol[r];
        int qrw = q0 + quad * 4 + r;
        for (int dt = 0; dt < 4; ++dt) {
            int ch = h * HD + dt * 16 + l16;
            attn_out[((size_t)b * S_ + qrw) * C_ + ch] = f2bf(o[dt][r] * inv);
        }
    }
}

// ---------------------------------------------------------------- launch
extern "C" void kernel_launch(void* const* d_in, const int* in_sizes, int n_in,
                              void* d_out, int out_size, void* d_ws, size_t ws_size,
                              hipStream_t stream) {
    const float* x        = (const float*)d_in[0];
    const float* gn_scale = (const float*)d_in[2];
    const float* gn_bias  = (const float*)d_in[3];
    const float* w_qkv    = (const float*)d_in[4];
    const float* b_qkv    = (const float*)d_in[5];
    const float* w_out    = (const float*)d_in[6];
    const float* b_out    = (const float*)d_in[7];
    float* out = (float*)d_out;

    char* ws = (char*)d_ws;
    unsigned short* xn    = (unsigned short*)(ws);                          // 8 MB
    unsigned short* kq    = (unsigned short*)(ws + ((size_t)8  << 20));     // 16 MB
    unsigned short* attn  = (unsigned short*)(ws + ((size_t)24 << 20));     // 8 MB
    unsigned short* vT    = (unsigned short*)(ws + ((size_t)32 << 20));     // 8 MB
    unsigned short* wqkvT = (unsigned short*)(ws + ((size_t)40 << 20));     // 1.5 MB
    unsigned short* woutT = (unsigned short*)(ws + ((size_t)40 << 20) + ((size_t)3 << 19)); // 0.5 MB

    prep_kernel<<<dim3(1280), 256, 0, stream>>>(
        w_qkv, w_out, wqkvT, woutT, x, gn_scale, gn_bias, xn);

    gemm_kernel<0><<<dim3(QKVC / 128, (B_ * S_) / 128), 256, 0, stream>>>(
        xn, wqkvT, b_qkv, nullptr, kq, vT, nullptr, B_ * S_, QKVC, C_);

    attn_kernel<<<dim3(1024), 256, 0, stream>>>(kq, vT, attn);

    gemm_kernel<1><<<dim3(C_ / 128, (B_ * S_) / 128), 256, 0, stream>>>(
        attn, woutT, b_out, xn, nullptr, nullptr, out, B_ * S_, C_, C_);
}

// Round 12
// 157.216 us; speedup vs baseline: 2.1515x; 1.0189x over previous
//
#include <hip/hip_runtime.h>
#include <hip/hip_bf16.h>

// AttentionBlock: GroupNorm -> QKV -> MHA (8 heads, hd=64, s=1024) -> out proj -> +xn
// Inputs/outputs FP32; internally bf16 for MFMA.
//
// r12: (1) gn caches x as bf16 in LDS between reduce/normalize passes
// (single HBM read of x); (2) attention processes 64 keys/iter (two proven
// 32-key sub-bodies per barrier -> 16 barriers instead of 32).
// Attn r11 core: S^T=K@Q^T, P built in registers as PV A-frag under key
// relabeling sigma(kh,quad,r)=8*quad+4*kh+r, V staged with same permutation.
//
// ws: xn 8MB @0 | kq 16MB @8 | attn 8MB @24 | vT 8MB @32 | wqkvT 1.5MB @40 | woutT .5MB @41.5

#define B_    8
#define S_    1024
#define C_    512
#define NH    8
#define HD    64
#define QKVC  1536
#define GROUPS 32
#define GSIZE  16
#define EPSV   1e-5f
#define QSCL  0.18033688f   // 0.125 * log2(e)

using frag8 = __attribute__((ext_vector_type(8))) short;   // 8 bf16 = 4 VGPR
using f32x4 = __attribute__((ext_vector_type(4))) float;

__device__ __forceinline__ float bf2f(unsigned short u) {
    union { unsigned int i; float f; } v; v.i = ((unsigned int)u) << 16; return v.f;
}
__device__ __forceinline__ unsigned short f2bf(float f) {
    union { float f; unsigned int i; } v; v.f = f;
    unsigned int x = v.i;
    return (unsigned short)((x + 0x7fffu + ((x >> 16) & 1u)) >> 16);
}
// pack two fp32 -> two bf16 (round-half-up) in one dword: low=a, high=b
__device__ __forceinline__ unsigned int pk2bf(float a, float b) {
    union { float f; unsigned int u; } x, y; x.f = a; y.f = b;
    return __builtin_amdgcn_perm(y.u + 0x8000u, x.u + 0x8000u, 0x07060302u);
}
__device__ __forceinline__ float fexp2(float x) {
#if __has_builtin(__builtin_amdgcn_exp2f)
    return __builtin_amdgcn_exp2f(x);
#else
    return exp2f(x);
#endif
}
__device__ __forceinline__ f32x4 zero4() {
    f32x4 z; z[0] = 0.f; z[1] = 0.f; z[2] = 0.f; z[3] = 0.f; return z;
}
__device__ __forceinline__ void gl_lds(const unsigned short* gp, unsigned short* lp) {
    __builtin_amdgcn_global_load_lds(
        (const __attribute__((address_space(1))) void*)gp,
        (__attribute__((address_space(3))) void*)lp, 16, 0, 0);
}

// ---------------------------------------------------------------- prep
// blocks 0..767: transpose w_qkv; 768..1023: transpose w_out; 1024..1279: gn
__global__ __launch_bounds__(256) void prep_kernel(
        const float* __restrict__ w_qkv, const float* __restrict__ w_out,
        unsigned short* __restrict__ wqkvT, unsigned short* __restrict__ woutT,
        const float* __restrict__ x,
        const float* __restrict__ scale, const float* __restrict__ bias,
        unsigned short* __restrict__ xn) {
    __shared__ unsigned short xcache[16384];     // gn: bf16 x cache (32 KB)
    __shared__ float s_red[8];
    int id = blockIdx.x;
    int t = threadIdx.x;
    if (id < 1024) {
        float* tile = (float*)xcache;            // reuse as 32x33 fp32 tile
        const float* in; unsigned short* out; int N, n0, k0;
        if (id < 768) { in = w_qkv; out = wqkvT; N = QKVC; n0 = (id % 48) * 32; k0 = (id / 48) * 32; }
        else { int i2 = id - 768; in = w_out; out = woutT; N = C_; n0 = (i2 % 16) * 32; k0 = (i2 / 16) * 32; }
        for (int i = 0; i < 4; ++i) {
            int idx = t + i * 256; int r = idx >> 5, c = idx & 31;
            tile[r * 33 + c] = in[(size_t)(k0 + r) * N + n0 + c];
        }
        __syncthreads();
        for (int i = 0; i < 4; ++i) {
            int idx = t + i * 256; int r = idx >> 5, c = idx & 31;
            out[(size_t)(n0 + r) * C_ + k0 + c] = f2bf(tile[c * 33 + r]);
        }
        return;
    }
    // ---- groupnorm: pass 1 reads fp32 x, sums, caches bf16 in LDS;
    //      pass 2 normalizes from LDS (x read from HBM exactly once).
    int bg = id - 1024;
    int b = bg >> 5, g = bg & 31;
    const float* xb = x + (size_t)b * S_ * C_;

    float sum = 0.f, ss = 0.f;
    for (int i = 0; i < 16; ++i) {
        int idx = t + i * 256;                   // 0..4095 float4 segments
        int row = idx >> 2, j = idx & 3;
        float4 v = *(const float4*)(xb + (size_t)row * C_ + g * GSIZE + j * 4);
        sum += v.x + v.y + v.z + v.w;
        ss  += v.x * v.x + v.y * v.y + v.z * v.z + v.w * v.w;
        uint2 c;
        c.x = pk2bf(v.x, v.y);
        c.y = pk2bf(v.z, v.w);
        *(uint2*)(&xcache[idx * 4]) = c;
    }
    for (int off = 1; off < 64; off <<= 1) {
        sum += __shfl_xor(sum, off);
        ss  += __shfl_xor(ss,  off);
    }
    int wid = t >> 6;
    if ((t & 63) == 0) { s_red[wid] = sum; s_red[4 + wid] = ss; }
    __syncthreads();
    sum = s_red[0] + s_red[1] + s_red[2] + s_red[3];
    ss  = s_red[4] + s_red[5] + s_red[6] + s_red[7];
    float mean = sum * (1.f / 16384.f);
    float var  = ss * (1.f / 16384.f) - mean * mean;
    float rinv = rsqrtf(var + EPSV);

    float sc[16], bi[16];
    for (int u = 0; u < 16; ++u) {
        sc[u] = scale[g * GSIZE + u];
        bi[u] = bias[g * GSIZE + u];
    }
    for (int i = 0; i < 16; ++i) {
        int idx = t + i * 256;
        int row = idx >> 2, j = idx & 3;
        uint2 c = *(const uint2*)(&xcache[idx * 4]);
        float v0 = bf2f((unsigned short)(c.x & 0xffffu));
        float v1 = bf2f((unsigned short)(c.x >> 16));
        float v2 = bf2f((unsigned short)(c.y & 0xffffu));
        float v3 = bf2f((unsigned short)(c.y >> 16));
        int c0 = j * 4;
        float f0 = (v0 - mean) * rinv * sc[c0 + 0] + bi[c0 + 0];
        float f1 = (v1 - mean) * rinv * sc[c0 + 1] + bi[c0 + 1];
        float f2 = (v2 - mean) * rinv * sc[c0 + 2] + bi[c0 + 2];
        float f3 = (v3 - mean) * rinv * sc[c0 + 3] + bi[c0 + 3];
        uint2 o;
        o.x = pk2bf(f0, f1);
        o.y = pk2bf(f2, f3);
        *(uint2*)(xn + (size_t)b * S_ * C_ + (size_t)row * C_ + g * GSIZE + c0) = o;
    }
}

// ---------------------------------------------------------------- GEMM
// (r9 version — 128x128 tile, BK=32, A+B via global_load_lds, double-buffered)
template<int MODE>
__global__ __launch_bounds__(256) void gemm_kernel(
        const unsigned short* __restrict__ A,
        const unsigned short* __restrict__ Bt,
        const float* __restrict__ bias,
        const unsigned short* __restrict__ resid,
        unsigned short* __restrict__ outA,   // MODE0: kq [M][1024]
        unsigned short* __restrict__ outV,   // MODE0: vT [b][h][64][1024]
        float* __restrict__ outF,            // MODE1: fp32 [M][N]
        int M, int N, int K) {
    __shared__ unsigned short As[2][128 * 32];
    __shared__ unsigned short Bs[2][128 * 32];
    int m0 = blockIdx.y * 128, n0 = blockIdx.x * 128;
    int t = threadIdx.x;
    int wid = t >> 6, lane = t & 63;
    int quad = lane >> 4, l16 = lane & 15;
    int wm = (wid >> 1) * 64, wn = (wid & 1) * 64;

    f32x4 acc[4][4];
    for (int mi = 0; mi < 4; ++mi)
        for (int ni = 0; ni < 4; ++ni) acc[mi][ni] = zero4();

    int srow = t >> 2, sseg = t & 3;             // staging roles
    auto stage = [&](int k0, int buf) {
        for (int i = 0; i < 2; ++i) {
            gl_lds(A + (size_t)(m0 + i * 64 + srow) * K + k0 + sseg * 8,
                   &As[buf][(size_t)(i * 256 + wid * 64) * 8]);
            gl_lds(Bt + (size_t)(n0 + i * 64 + srow) * K + k0 + sseg * 8,
                   &Bs[buf][(size_t)(i * 256 + wid * 64) * 8]);
        }
    };

    stage(0, 0);
    int nk = K >> 5;
    for (int i = 0; i < nk; ++i) {
        __syncthreads();
        if (i + 1 < nk) stage((i + 1) << 5, (i + 1) & 1);
        int buf = i & 1;

        frag8 bfrag[4], afrag[4];
        for (int ni = 0; ni < 4; ++ni)
            bfrag[ni] = *(const frag8*)(&Bs[buf][(wn + ni * 16 + l16) * 32 + quad * 8]);
        for (int mi = 0; mi < 4; ++mi)
            afrag[mi] = *(const frag8*)(&As[buf][(wm + mi * 16 + l16) * 32 + quad * 8]);

        for (int mi = 0; mi < 4; ++mi)
            for (int ni = 0; ni < 4; ++ni)
                acc[mi][ni] = __builtin_amdgcn_mfma_f32_16x16x32_bf16(
                    afrag[mi], bfrag[ni], acc[mi][ni], 0, 0, 0);
    }

    for (int ni = 0; ni < 4; ++ni) {
        int c0 = n0 + wn + ni * 16;
        float bv = bias[c0 + l16];
        if (MODE == 0) {
            int h = c0 / 192, rr = c0 % 192;
            if (rr >= 128) {
                int d = rr - 128 + l16;
                int bidx = m0 >> 10;
                unsigned short* vp = outV + (((size_t)bidx * NH + h) * HD + d) * S_
                                   + (m0 & 1023) + wm + quad * 4;
                for (int mi = 0; mi < 4; ++mi) {
                    uint2 pk;
                    pk.x = pk2bf(acc[mi][ni][0] + bv, acc[mi][ni][1] + bv);
                    pk.y = pk2bf(acc[mi][ni][2] + bv, acc[mi][ni][3] + bv);
                    *(uint2*)(vp + mi * 16) = pk;
                }
            } else {
                float scl = (rr < 64) ? QSCL : 1.0f;   // q pre-scaled by log2e/8
                int colk = h * 128 + rr + l16;
                for (int mi = 0; mi < 4; ++mi)
                    for (int r = 0; r < 4; ++r) {
                        int row = m0 + wm + mi * 16 + quad * 4 + r;
                        outA[(size_t)row * 1024 + colk] = f2bf((acc[mi][ni][r] + bv) * scl);
                    }
            }
        } else {
            int col = c0 + l16;
            for (int mi = 0; mi < 4; ++mi)
                for (int r = 0; r < 4; ++r) {
                    int row = m0 + wm + mi * 16 + quad * 4 + r;
                    float v = acc[mi][ni][r] + bv + bf2f(resid[(size_t)row * N + col]);
                    outF[(size_t)row * N + col] = v;
                }
        }
    }
}

// ---------------------------------------------------------------- attention
// 1024 blocks (XCD-swizzled), 4 waves x 16 q-rows, 64 keys/iter (two 32-key
// sub-bodies per barrier -> 16 barriers). r11 core: S^T=K@Q^T, P in registers
// as PV A-frag (key relabeling), V staged permuted, l via ones-MFMA.
__global__ __launch_bounds__(256) void attn_kernel(
        const unsigned short* __restrict__ kq,   // [b*s][h*128 + (q|k)]
        const unsigned short* __restrict__ vT,   // [b][h][d][s]
        unsigned short* __restrict__ attn_out) { // [b][s][512]
    int i = blockIdx.x;
    int xcd = i & 7, slot = i >> 3;              // slot 0..127
    int bh = xcd * 8 + (slot >> 4);              // 8 (b,h) pairs per XCD
    int qt = slot & 15;
    int b = bh >> 3, h = bh & 7;

    int t = threadIdx.x;
    int wid = t >> 6, lane = t & 63, quad = lane >> 4, l16 = lane & 15;
    int q0 = qt * 64 + wid * 16;

    __shared__ unsigned short Ks[2][2][2048];    // [buf][key-half 32][dh][key32][d32]
    __shared__ unsigned short Vs[2][2][2048];    // [buf][key-half][d64][pos32]

    // Q B-fragments: B[n=q][k=d] (one-time scattered load, prologue only)
    const unsigned short* qrow = kq + ((size_t)b * S_ + q0 + l16) * 1024 + h * 128;
    frag8 qf0 = *(const frag8*)(qrow + quad * 8);
    frag8 qf1 = *(const frag8*)(qrow + 32 + quad * 8);

    frag8 ones;
    for (int i2 = 0; i2 < 8; ++i2) ones[i2] = (short)0x3f80;   // bf16 1.0

    f32x4 o[4], ol;
    ol = zero4();
    for (int dt = 0; dt < 4; ++dt) o[dt] = zero4();

    const unsigned short* kbase = kq + (size_t)b * S_ * 1024 + h * 128 + 64;
    const unsigned short* vbase = vT + ((size_t)b * NH + h) * HD * S_;

    // K staging roles (gl_lds, wave-uniform LDS base)
    int kdh = wid & 1, krh = wid >> 1;
    int krow = krh * 16 + (lane >> 2);
    int kseg = lane & 3;
    // V staging roles (explicit load + permuted b64 writes)
    int vd = wid * 16 + (lane >> 2);             // d row 0..63
    int vseg = lane & 3;                         // true-key segment (8 keys)
    int vkh = vseg >> 1, vsp = vseg & 1;
    int vbase1 = vsp * 16 + vkh * 4;             // pos of u=0..3; +8 for u=4..7

    auto stageK = [&](int j0, int buf, int half) {
        gl_lds(kbase + (size_t)(j0 + krow) * 1024 + kdh * 32 + kseg * 8,
               &Ks[buf][half][kdh * 1024 + krh * 512]);
    };
    auto loadV = [&](int j0) {
        return *(const uint4*)(vbase + (size_t)vd * S_ + j0 + vseg * 8);
    };
    auto writeV = [&](uint4 w, int buf, int half) {
        unsigned short* vdst = &Vs[buf][half][vd * 32];
        uint2 g1; g1.x = w.x; g1.y = w.y;
        uint2 g2; g2.x = w.z; g2.y = w.w;
        *(uint2*)(vdst + vbase1)     = g1;
        *(uint2*)(vdst + vbase1 + 8) = g2;
    };

    stageK(0, 0, 0);  stageK(32, 0, 1);
    writeV(loadV(0), 0, 0);  writeV(loadV(32), 0, 1);

    for (int it = 0; it < S_ / 64; ++it) {
        int cur = it & 1, nxt = cur ^ 1;
        __syncthreads();                          // staging of cur visible
        uint4 vn0, vn1;
        bool more = (it < S_ / 64 - 1);
        if (more) {
            int jn = (it + 1) * 64;
            stageK(jn, nxt, 0);
            stageK(jn + 32, nxt, 1);
            vn0 = loadV(jn);
            vn1 = loadV(jn + 32);
        }

        for (int half = 0; half < 2; ++half) {
            // K frags from LDS (A-operand): A[m=key=kh*16+l16][k=d]
            frag8 kf[2][2];
            for (int kh = 0; kh < 2; ++kh)
                for (int dh = 0; dh < 2; ++dh)
                    kf[kh][dh] = *(const frag8*)(&Ks[cur][half][dh * 1024 + (kh * 16 + l16) * 32 + quad * 8]);

            // S^T = K @ Q^T : lane holds S^T[key=kh*16+quad*4+r][q=l16]
            f32x4 s[2];
            for (int kh = 0; kh < 2; ++kh) {
                f32x4 acc = zero4();
                acc = __builtin_amdgcn_mfma_f32_16x16x32_bf16(kf[kh][0], qf0, acc, 0, 0, 0);
                acc = __builtin_amdgcn_mfma_f32_16x16x32_bf16(kf[kh][1], qf1, acc, 0, 0, 0);
                s[kh] = acc;
            }

            // P A-frag in registers (relabeled positions)
            union { frag8 f; unsigned int u[4]; } pfu;
            pfu.u[0] = pk2bf(fexp2(s[0][0]), fexp2(s[0][1]));
            pfu.u[1] = pk2bf(fexp2(s[0][2]), fexp2(s[0][3]));
            pfu.u[2] = pk2bf(fexp2(s[1][0]), fexp2(s[1][1]));
            pfu.u[3] = pk2bf(fexp2(s[1][2]), fexp2(s[1][3]));

            // V frags from LDS (permuted positions): B[n=d][k=pos=quad*8+j]
            frag8 vf[4];
            for (int dt = 0; dt < 4; ++dt)
                vf[dt] = *(const frag8*)(&Vs[cur][half][(dt * 16 + l16) * 32 + quad * 8]);

            ol = __builtin_amdgcn_mfma_f32_16x16x32_bf16(pfu.f, ones, ol, 0, 0, 0);
            for (int dt = 0; dt < 4; ++dt)
                o[dt] = __builtin_amdgcn_mfma_f32_16x16x32_bf16(pfu.f, vf[dt], o[dt], 0, 0, 0);
        }

        if (more) {
            writeV(vn0, nxt, 0);                  // visible after next barrier
            writeV(vn1, nxt, 1);
        }
    }

    // O C-layout: lane(quad,l16) holds O[q=quad*4+r][d=dt*16+l16]; ol same rows
    for (int r = 0; r < 4; ++r) {
        float inv = 1.0f / ol[r];
        int qrw = q0 + quad * 4 + r;
        for (int dt = 0; dt < 4; ++dt) {
            int ch = h * HD + dt * 16 + l16;
            attn_out[((size_t)b * S_ + qrw) * C_ + ch] = f2bf(o[dt][r] * inv);
        }
    }
}

// ---------------------------------------------------------------- launch
extern "C" void kernel_launch(void* const* d_in, const int* in_sizes, int n_in,
                              void* d_out, int out_size, void* d_ws, size_t ws_size,
                              hipStream_t stream) {
    const float* x        = (const float*)d_in[0];
    const float* gn_scale = (const float*)d_in[2];
    const float* gn_bias  = (const float*)d_in[3];
    const float* w_qkv    = (const float*)d_in[4];
    const float* b_qkv    = (const float*)d_in[5];
    const float* w_out    = (const float*)d_in[6];
    const float* b_out    = (const float*)d_in[7];
    float* out = (float*)d_out;

    char* ws = (char*)d_ws;
    unsigned short* xn    = (unsigned short*)(ws);                          // 8 MB
    unsigned short* kq    = (unsigned short*)(ws + ((size_t)8  << 20));     // 16 MB
    unsigned short* attn  = (unsigned short*)(ws + ((size_t)24 << 20));     // 8 MB
    unsigned short* vT    = (unsigned short*)(ws + ((size_t)32 << 20));     // 8 MB
    unsigned short* wqkvT = (unsigned short*)(ws + ((size_t)40 << 20));     // 1.5 MB
    unsigned short* woutT = (unsigned short*)(ws + ((size_t)40 << 20) + ((size_t)3 << 19)); // 0.5 MB

    prep_kernel<<<dim3(1280), 256, 0, stream>>>(
        w_qkv, w_out, wqkvT, woutT, x, gn_scale, gn_bias, xn);

    gemm_kernel<0><<<dim3(QKVC / 128, (B_ * S_) / 128), 256, 0, stream>>>(
        xn, wqkvT, b_qkv, nullptr, kq, vT, nullptr, B_ * S_, QKVC, C_);

    attn_kernel<<<dim3(1024), 256, 0, stream>>>(kq, vT, attn);

    gemm_kernel<1><<<dim3(C_ / 128, (B_ * S_) / 128), 256, 0, stream>>>(
        attn, woutT, b_out, xn, nullptr, nullptr, out, B_ * S_, C_, C_);
}